// Round 1
// baseline (4213.080 us; speedup 1.0000x reference)
//
#include <hip/hip_runtime.h>

#define N_NODES 50000
#define N_EDGES 800000
#define N_SUP   3
#define FD      128

// ---------------------------------------------------------------------------
// out = 0
__global__ __launch_bounds__(256) void init_out_kernel(float4* __restrict__ out) {
    int i = blockIdx.x * 256 + threadIdx.x;
    if (i < N_NODES * (FD / 4)) out[i] = make_float4(0.f, 0.f, 0.f, 0.f);
}

// ---------------------------------------------------------------------------
// sup[M,128] = x[M,128] @ W[128,128]   (f32, LDS-tiled)
// Block = 256 threads, BM = 32 rows. LDS: xS 32x129 (16.5KB) + W chunk 16KB.
__global__ __launch_bounds__(256) void gemm_kernel(const float* __restrict__ x,
                                                   const float* __restrict__ W,
                                                   float* __restrict__ sup) {
    __shared__ float  xS[32][FD + 1];   // +1 pad: conflict-free row-broadcast reads
    __shared__ float4 wS[32 * 32];      // 32 kk-rows x 32 float4 (128 cols)

    const int t    = threadIdx.x;
    const int row0 = blockIdx.x * 32;
    const float4* x4 = (const float4*)x;
    const float4* W4 = (const float4*)W;

    // stage x tile: 32 rows x 32 float4
    for (int i = t; i < 32 * 32; i += 256) {
        int r = i >> 5, c = i & 31;
        int gr = row0 + r;
        float4 v = (gr < N_NODES) ? x4[(size_t)gr * 32 + c] : make_float4(0, 0, 0, 0);
        xS[r][c * 4 + 0] = v.x;
        xS[r][c * 4 + 1] = v.y;
        xS[r][c * 4 + 2] = v.z;
        xS[r][c * 4 + 3] = v.w;
    }

    const int tx = t & 31;   // col group: cols tx*4 .. tx*4+3
    const int ty = t >> 5;   // row group: rows ty*4 .. ty*4+3
    float acc[4][4] = {{0.f}};

    for (int k0 = 0; k0 < FD; k0 += 32) {
        __syncthreads();                       // xS ready (iter 0) / prev chunk consumed
        for (int i = t; i < 1024; i += 256) wS[i] = W4[k0 * 32 + i];
        __syncthreads();
        #pragma unroll 8
        for (int kk = 0; kk < 32; ++kk) {
            float4 wv = wS[kk * 32 + tx];
            #pragma unroll
            for (int r = 0; r < 4; ++r) {
                float xv = xS[ty * 4 + r][k0 + kk];
                acc[r][0] += xv * wv.x;
                acc[r][1] += xv * wv.y;
                acc[r][2] += xv * wv.z;
                acc[r][3] += xv * wv.w;
            }
        }
    }

    float4* sup4 = (float4*)sup;
    #pragma unroll
    for (int r = 0; r < 4; ++r) {
        int gr = row0 + ty * 4 + r;
        if (gr < N_NODES)
            sup4[(size_t)gr * 32 + tx] =
                make_float4(acc[r][0], acc[r][1], acc[r][2], acc[r][3]);
    }
}

// ---------------------------------------------------------------------------
// out[rows[e],:] += vals[e] * sup[cols[e],:]   (32 lanes per edge, float4)
__global__ __launch_bounds__(256) void scatter_kernel(const float4* __restrict__ sup,
                                                      const int* __restrict__ rows,
                                                      const int* __restrict__ cols,
                                                      const float* __restrict__ vals,
                                                      float* __restrict__ out) {
    int gt   = blockIdx.x * 256 + threadIdx.x;
    int e    = gt >> 5;
    int lane = gt & 31;
    if (e >= N_EDGES) return;

    int   r = rows[e];
    int   c = cols[e];
    float v = vals[e];

    float4 g = sup[(size_t)c * 32 + lane];
    float* dst = out + (size_t)r * FD + lane * 4;
    atomicAdd(dst + 0, g.x * v);
    atomicAdd(dst + 1, g.y * v);
    atomicAdd(dst + 2, g.z * v);
    atomicAdd(dst + 3, g.w * v);
}

// ---------------------------------------------------------------------------
// out = relu(out + bias)
__global__ __launch_bounds__(256) void bias_relu_kernel(float4* __restrict__ out,
                                                        const float4* __restrict__ bias4) {
    int i = blockIdx.x * 256 + threadIdx.x;
    if (i >= N_NODES * (FD / 4)) return;
    float4 b = bias4[i & 31];
    float4 o = out[i];
    o.x = fmaxf(o.x + b.x, 0.f);
    o.y = fmaxf(o.y + b.y, 0.f);
    o.z = fmaxf(o.z + b.z, 0.f);
    o.w = fmaxf(o.w + b.w, 0.f);
    out[i] = o;
}

// ---------------------------------------------------------------------------
extern "C" void kernel_launch(void* const* d_in, const int* in_sizes, int n_in,
                              void* d_out, int out_size, void* d_ws, size_t ws_size,
                              hipStream_t stream) {
    const float* x    = (const float*)d_in[0];
    const int*   rows = (const int*)d_in[1];
    const int*   cols = (const int*)d_in[2];
    const float* vals = (const float*)d_in[3];
    const float* kern = (const float*)d_in[4];
    const float* bias = (const float*)d_in[5];
    float* out = (float*)d_out;
    float* sup = (float*)d_ws;   // N_NODES * FD floats = 25.6 MB scratch

    const int vec_blocks  = (N_NODES * (FD / 4) + 255) / 256;
    const int gemm_blocks = (N_NODES + 31) / 32;
    const int scat_blocks = (N_EDGES * 32 + 255) / 256;

    init_out_kernel<<<vec_blocks, 256, 0, stream>>>((float4*)out);

    for (int k = 0; k < N_SUP; ++k) {
        gemm_kernel<<<gemm_blocks, 256, 0, stream>>>(
            x, kern + (size_t)k * FD * FD, sup);
        scatter_kernel<<<scat_blocks, 256, 0, stream>>>(
            (const float4*)sup,
            rows + (size_t)k * N_EDGES,
            cols + (size_t)k * N_EDGES,
            vals + (size_t)k * N_EDGES,
            out);
    }

    bias_relu_kernel<<<vec_blocks, 256, 0, stream>>>(
        (float4*)out, (const float4*)bias);
}

// Round 2
// 736.702 us; speedup vs baseline: 5.7188x; 5.7188x over previous
//
#include <hip/hip_runtime.h>

#define N_NODES 50000
#define N_EDGES 800000
#define N_SUP   3
#define FD      128

#define SCAN_CHUNK 1024
#define NB_SCAN ((N_NODES + SCAN_CHUNK - 1) / SCAN_CHUNK)   // 49

// ---------------------------------------------------------------------------
// sup[M,128] = x[M,128] @ W[128,128]   (f32, LDS-tiled)
__global__ __launch_bounds__(256) void gemm_kernel(const float* __restrict__ x,
                                                   const float* __restrict__ W,
                                                   float* __restrict__ sup) {
    __shared__ float  xS[32][FD + 1];
    __shared__ float4 wS[32 * 32];

    const int t    = threadIdx.x;
    const int row0 = blockIdx.x * 32;
    const float4* x4 = (const float4*)x;
    const float4* W4 = (const float4*)W;

    for (int i = t; i < 32 * 32; i += 256) {
        int r = i >> 5, c = i & 31;
        int gr = row0 + r;
        float4 v = (gr < N_NODES) ? x4[(size_t)gr * 32 + c] : make_float4(0, 0, 0, 0);
        xS[r][c * 4 + 0] = v.x;
        xS[r][c * 4 + 1] = v.y;
        xS[r][c * 4 + 2] = v.z;
        xS[r][c * 4 + 3] = v.w;
    }

    const int tx = t & 31;
    const int ty = t >> 5;
    float acc[4][4] = {{0.f}};

    for (int k0 = 0; k0 < FD; k0 += 32) {
        __syncthreads();
        for (int i = t; i < 1024; i += 256) wS[i] = W4[k0 * 32 + i];
        __syncthreads();
        #pragma unroll 8
        for (int kk = 0; kk < 32; ++kk) {
            float4 wv = wS[kk * 32 + tx];
            #pragma unroll
            for (int r = 0; r < 4; ++r) {
                float xv = xS[ty * 4 + r][k0 + kk];
                acc[r][0] += xv * wv.x;
                acc[r][1] += xv * wv.y;
                acc[r][2] += xv * wv.z;
                acc[r][3] += xv * wv.w;
            }
        }
    }

    float4* sup4 = (float4*)sup;
    #pragma unroll
    for (int r = 0; r < 4; ++r) {
        int gr = row0 + ty * 4 + r;
        if (gr < N_NODES)
            sup4[(size_t)gr * 32 + tx] =
                make_float4(acc[r][0], acc[r][1], acc[r][2], acc[r][3]);
    }
}

// ---------------------------------------------------------------------------
__global__ __launch_bounds__(256) void zero2_kernel(int* __restrict__ a,
                                                    int* __restrict__ b) {
    int i = blockIdx.x * 256 + threadIdx.x;
    if (i < N_NODES) { a[i] = 0; b[i] = 0; }
}

__global__ __launch_bounds__(256) void hist_kernel(const int* __restrict__ rows,
                                                   int* __restrict__ counts) {
    int e = blockIdx.x * 256 + threadIdx.x;
    if (e < N_EDGES) atomicAdd(&counts[rows[e]], 1);
}

// per-1024-chunk total
__global__ __launch_bounds__(256) void blocksum_kernel(const int* __restrict__ counts,
                                                       int* __restrict__ bs) {
    __shared__ int s[256];
    int b = blockIdx.x, t = threadIdx.x;
    int base = b * SCAN_CHUNK;
    int sum = 0;
    for (int j = t; j < SCAN_CHUNK; j += 256) {
        int idx = base + j;
        sum += (idx < N_NODES) ? counts[idx] : 0;
    }
    s[t] = sum; __syncthreads();
    for (int off = 128; off > 0; off >>= 1) {
        if (t < off) s[t] += s[t + off];
        __syncthreads();
    }
    if (t == 0) bs[b] = s[0];
}

// exclusive scan of NB_SCAN block sums (tiny, serial)
__global__ void scan_bs_kernel(int* __restrict__ bs) {
    if (threadIdx.x == 0 && blockIdx.x == 0) {
        int acc = 0;
        for (int i = 0; i < NB_SCAN; ++i) { int v = bs[i]; bs[i] = acc; acc += v; }
    }
}

// per-chunk exclusive scan + chunk offset -> row_start
__global__ __launch_bounds__(256) void scan_chunk_kernel(const int* __restrict__ counts,
                                                         const int* __restrict__ bs,
                                                         int* __restrict__ row_start) {
    __shared__ int s[256];
    int b = blockIdx.x, t = threadIdx.x;
    int base = b * SCAN_CHUNK + t * 4;
    int c0 = (base + 0 < N_NODES) ? counts[base + 0] : 0;
    int c1 = (base + 1 < N_NODES) ? counts[base + 1] : 0;
    int c2 = (base + 2 < N_NODES) ? counts[base + 2] : 0;
    int c3 = (base + 3 < N_NODES) ? counts[base + 3] : 0;
    int local = c0 + c1 + c2 + c3;
    int val = local;
    s[t] = val; __syncthreads();
    for (int off = 1; off < 256; off <<= 1) {
        int v = (t >= off) ? s[t - off] : 0;
        __syncthreads();
        val += v; s[t] = val;
        __syncthreads();
    }
    int excl = bs[b] + val - local;
    if (base + 0 < N_NODES) row_start[base + 0] = excl;
    if (base + 1 < N_NODES) row_start[base + 1] = excl + c0;
    if (base + 2 < N_NODES) row_start[base + 2] = excl + c0 + c1;
    if (base + 3 < N_NODES) row_start[base + 3] = excl + c0 + c1 + c2;
    if (b == 0 && t == 0) row_start[N_NODES] = N_EDGES;
}

// scatter edges into row buckets: payload = {col, val}
__global__ __launch_bounds__(256) void fill_kernel(const int* __restrict__ rows,
                                                   const int* __restrict__ cols,
                                                   const float* __restrict__ vals,
                                                   const int* __restrict__ row_start,
                                                   int* __restrict__ fill,
                                                   int2* __restrict__ payload) {
    int e = blockIdx.x * 256 + threadIdx.x;
    if (e >= N_EDGES) return;
    int r = rows[e];
    int pos = row_start[r] + atomicAdd(&fill[r], 1);
    payload[pos] = make_int2(cols[e], __float_as_int(vals[e]));
}

// one wave per row: acc[lane] = sum_e val_e * sup[col_e][lane*2..+1]
__global__ __launch_bounds__(256) void gather_kernel(const float2* __restrict__ sup2,
                                                     const int2* __restrict__ payload,
                                                     const int* __restrict__ row_start,
                                                     float2* __restrict__ out2,
                                                     const float2* __restrict__ bias2,
                                                     int first, int last) {
    int wid  = threadIdx.x >> 6;
    int lane = threadIdx.x & 63;
    int r = blockIdx.x * 4 + wid;
    if (r >= N_NODES) return;

    int s = row_start[r];
    int e = row_start[r + 1];

    float2 acc;
    if (first) acc = make_float2(0.f, 0.f);
    else       acc = out2[(size_t)r * 64 + lane];

    for (int i = s; i < e; ++i) {
        int2 p   = payload[i];                 // wave-uniform -> broadcast load
        float v  = __int_as_float(p.y);
        float2 g = sup2[(size_t)p.x * 64 + lane];
        acc.x += v * g.x;
        acc.y += v * g.y;
    }

    if (last) {
        float2 b = bias2[lane];
        acc.x = fmaxf(acc.x + b.x, 0.f);
        acc.y = fmaxf(acc.y + b.y, 0.f);
    }
    out2[(size_t)r * 64 + lane] = acc;
}

// ---------------------------------------------------------------------------
extern "C" void kernel_launch(void* const* d_in, const int* in_sizes, int n_in,
                              void* d_out, int out_size, void* d_ws, size_t ws_size,
                              hipStream_t stream) {
    const float* x    = (const float*)d_in[0];
    const int*   rows = (const int*)d_in[1];
    const int*   cols = (const int*)d_in[2];
    const float* vals = (const float*)d_in[3];
    const float* kern = (const float*)d_in[4];
    const float* bias = (const float*)d_in[5];
    float* out = (float*)d_out;

    char* ws = (char*)d_ws;
    const size_t OFF_SUP  = 0;                         // 25,600,000 B
    const size_t OFF_CNT  = 25600000;                  // 200,192 B
    const size_t OFF_RS   = OFF_CNT  + 200192;         // 200,192 B
    const size_t OFF_FILL = OFF_RS   + 200192;         // 200,192 B
    const size_t OFF_BS   = OFF_FILL + 200192;         // 256 B
    const size_t OFF_PAY  = OFF_BS   + 256;            // 6,400,000 B

    float* sup       = (float*)(ws + OFF_SUP);
    int*   counts    = (int*)  (ws + OFF_CNT);
    int*   row_start = (int*)  (ws + OFF_RS);
    int*   fillc     = (int*)  (ws + OFF_FILL);
    int*   bs        = (int*)  (ws + OFF_BS);
    int2*  payload   = (int2*) (ws + OFF_PAY);

    const int gemm_blocks = (N_NODES + 31) / 32;
    const int node_blocks = (N_NODES + 255) / 256;
    const int edge_blocks = (N_EDGES + 255) / 256;
    const int row_blocks  = (N_NODES + 3) / 4;

    for (int k = 0; k < N_SUP; ++k) {
        const int*   rk = rows + (size_t)k * N_EDGES;
        const int*   ck = cols + (size_t)k * N_EDGES;
        const float* vk = vals + (size_t)k * N_EDGES;

        gemm_kernel<<<gemm_blocks, 256, 0, stream>>>(
            x, kern + (size_t)k * FD * FD, sup);

        zero2_kernel<<<node_blocks, 256, 0, stream>>>(counts, fillc);
        hist_kernel<<<edge_blocks, 256, 0, stream>>>(rk, counts);
        blocksum_kernel<<<NB_SCAN, 256, 0, stream>>>(counts, bs);
        scan_bs_kernel<<<1, 64, 0, stream>>>(bs);
        scan_chunk_kernel<<<NB_SCAN, 256, 0, stream>>>(counts, bs, row_start);
        fill_kernel<<<edge_blocks, 256, 0, stream>>>(rk, ck, vk, row_start, fillc, payload);

        gather_kernel<<<row_blocks, 256, 0, stream>>>(
            (const float2*)sup, payload, row_start, (float2*)out,
            (const float2*)bias, k == 0 ? 1 : 0, k == N_SUP - 1 ? 1 : 0);
    }
}

// Round 4
// 559.512 us; speedup vs baseline: 7.5299x; 1.3167x over previous
//
#include <hip/hip_runtime.h>

#define N_NODES 50000
#define N_EDGES 800000
#define N_SUP   3
#define FD      128
#define NP_PAD  50176                 // padded per-support stride for int arrays

#define SCAN_CHUNK 1024
#define NB_SCAN ((N_NODES + SCAN_CHUNK - 1) / SCAN_CHUNK)   // 49

// ---------------------------------------------------------------------------
// CSR build kernels. Support index = kbase + blockIdx.y. Per-support work
// arrays are addressed with blockIdx.y * stride so the same kernels serve the
// batched (gridDim.y=3, stride=NP_PAD) and compact (gridDim.y=1, base ptrs
// pre-offset by caller via kbase) paths.
// ---------------------------------------------------------------------------
__global__ __launch_bounds__(256) void zero2_kernel(int* __restrict__ a,
                                                    int* __restrict__ b,
                                                    int stride) {
    int i = blockIdx.x * 256 + threadIdx.x;
    int off = blockIdx.y * stride;
    if (i < N_NODES) { a[off + i] = 0; b[off + i] = 0; }
}

__global__ __launch_bounds__(256) void hist_kernel(const int* __restrict__ rows,
                                                   int kbase,
                                                   int* __restrict__ counts,
                                                   int stride) {
    int e = blockIdx.x * 256 + threadIdx.x;
    if (e >= N_EDGES) return;
    int k = kbase + blockIdx.y;
    int r = rows[(size_t)k * N_EDGES + e];
    atomicAdd(&counts[blockIdx.y * stride + r], 1);
}

__global__ __launch_bounds__(256) void blocksum_kernel(const int* __restrict__ counts,
                                                       int cstride,
                                                       int* __restrict__ bs) {
    __shared__ int s[256];
    int b = blockIdx.x, t = threadIdx.x;
    const int* c = counts + blockIdx.y * cstride;
    int base = b * SCAN_CHUNK;
    int sum = 0;
    for (int j = t; j < SCAN_CHUNK; j += 256) {
        int idx = base + j;
        sum += (idx < N_NODES) ? c[idx] : 0;
    }
    s[t] = sum; __syncthreads();
    for (int off = 128; off > 0; off >>= 1) {
        if (t < off) s[t] += s[t + off];
        __syncthreads();
    }
    if (t == 0) bs[blockIdx.y * 64 + b] = s[0];
}

__global__ void scan_bs_kernel(int* __restrict__ bs) {
    if (threadIdx.x == 0) {
        int* p = bs + blockIdx.y * 64;
        int acc = 0;
        for (int i = 0; i < NB_SCAN; ++i) { int v = p[i]; p[i] = acc; acc += v; }
    }
}

__global__ __launch_bounds__(256) void scan_chunk_kernel(const int* __restrict__ counts,
                                                         int cstride,
                                                         const int* __restrict__ bs,
                                                         int* __restrict__ row_start,
                                                         int rstride) {
    __shared__ int s[256];
    int b = blockIdx.x, t = threadIdx.x;
    const int* c  = counts + blockIdx.y * cstride;
    int*       rs = row_start + blockIdx.y * rstride;
    int base = b * SCAN_CHUNK + t * 4;
    int c0 = (base + 0 < N_NODES) ? c[base + 0] : 0;
    int c1 = (base + 1 < N_NODES) ? c[base + 1] : 0;
    int c2 = (base + 2 < N_NODES) ? c[base + 2] : 0;
    int c3 = (base + 3 < N_NODES) ? c[base + 3] : 0;
    int local = c0 + c1 + c2 + c3;
    int val = local;
    s[t] = val; __syncthreads();
    for (int off = 1; off < 256; off <<= 1) {
        int v = (t >= off) ? s[t - off] : 0;
        __syncthreads();
        val += v; s[t] = val;
        __syncthreads();
    }
    int excl = bs[blockIdx.y * 64 + b] + val - local;
    if (base + 0 < N_NODES) rs[base + 0] = excl;
    if (base + 1 < N_NODES) rs[base + 1] = excl + c0;
    if (base + 2 < N_NODES) rs[base + 2] = excl + c0 + c1;
    if (base + 3 < N_NODES) rs[base + 3] = excl + c0 + c1 + c2;
    if (b == 0 && t == 0) rs[N_NODES] = N_EDGES;
}

__global__ __launch_bounds__(256) void fill_kernel(const int* __restrict__ rows,
                                                   const int* __restrict__ cols,
                                                   const float* __restrict__ vals,
                                                   int kbase,
                                                   const int* __restrict__ row_start,
                                                   int rstride,
                                                   int* __restrict__ fillc,
                                                   int fstride,
                                                   int2* __restrict__ payload,
                                                   int pstride) {
    int e = blockIdx.x * 256 + threadIdx.x;
    if (e >= N_EDGES) return;
    int k = kbase + blockIdx.y;
    size_t ge = (size_t)k * N_EDGES + e;
    int r = rows[ge];
    int pos = row_start[blockIdx.y * rstride + r] +
              atomicAdd(&fillc[blockIdx.y * fstride + r], 1);
    payload[(size_t)blockIdx.y * pstride + pos] =
        make_int2(cols[ge], __float_as_int(vals[ge]));
}

// ---------------------------------------------------------------------------
// z[r, blockIdx.y*128 : +128] = sum_e val_e * x[col_e, :]
// One wave per row; lane owns a float2; 4 edges in flight (latency hiding).
__global__ __launch_bounds__(256) void gather_kernel(const float2* __restrict__ x2,
                                                     const int2* __restrict__ payload,
                                                     int pstride,
                                                     const int* __restrict__ row_start,
                                                     int rstride,
                                                     float2* __restrict__ z2,
                                                     int ldz2) {
    int wid  = threadIdx.x >> 6;
    int lane = threadIdx.x & 63;
    int r = blockIdx.x * 4 + wid;
    if (r >= N_NODES) return;

    const int*  rs  = row_start + blockIdx.y * rstride;
    const int2* pay = payload + (size_t)blockIdx.y * pstride;
    int s = rs[r];
    int e = rs[r + 1];

    float2 a0 = {0.f, 0.f}, a1 = {0.f, 0.f}, a2 = {0.f, 0.f}, a3 = {0.f, 0.f};
    int i = s;
    for (; i + 4 <= e; i += 4) {
        int2 p0 = pay[i + 0], p1 = pay[i + 1], p2 = pay[i + 2], p3 = pay[i + 3];
        float2 g0 = x2[(size_t)p0.x * 64 + lane];
        float2 g1 = x2[(size_t)p1.x * 64 + lane];
        float2 g2 = x2[(size_t)p2.x * 64 + lane];
        float2 g3 = x2[(size_t)p3.x * 64 + lane];
        float v0 = __int_as_float(p0.y), v1 = __int_as_float(p1.y);
        float v2 = __int_as_float(p2.y), v3 = __int_as_float(p3.y);
        a0.x = fmaf(v0, g0.x, a0.x); a0.y = fmaf(v0, g0.y, a0.y);
        a1.x = fmaf(v1, g1.x, a1.x); a1.y = fmaf(v1, g1.y, a1.y);
        a2.x = fmaf(v2, g2.x, a2.x); a2.y = fmaf(v2, g2.y, a2.y);
        a3.x = fmaf(v3, g3.x, a3.x); a3.y = fmaf(v3, g3.y, a3.y);
    }
    for (; i < e; ++i) {
        int2 p = pay[i];
        float v = __int_as_float(p.y);
        float2 g = x2[(size_t)p.x * 64 + lane];
        a0.x = fmaf(v, g.x, a0.x); a0.y = fmaf(v, g.y, a0.y);
    }
    float2 acc = make_float2((a0.x + a1.x) + (a2.x + a3.x),
                             (a0.y + a1.y) + (a2.y + a3.y));
    z2[(size_t)r * ldz2 + blockIdx.y * 64 + lane] = acc;
}

// ---------------------------------------------------------------------------
// out[64-row tile, 128] (+)= z[tile, K] @ W[K,128]; optional init / bias+relu.
// Block 256 = (tx 0..31 col-float4) x (ty 0..7, 8 rows each). BM=64.
__global__ __launch_bounds__(256) void gemm_kernel(const float* __restrict__ z,
                                                   int ldz4, int K,
                                                   const float* __restrict__ W,
                                                   const float* __restrict__ bias,
                                                   float* __restrict__ out,
                                                   int init, int final_) {
    __shared__ float  zS[64 * 32];
    __shared__ float4 wS[32 * 32];

    const int t    = threadIdx.x;
    const int row0 = blockIdx.x * 64;
    const int tx = t & 31;
    const int ty = t >> 5;
    const float4* z4 = (const float4*)z;
    const float4* W4 = (const float4*)W;

    float4 acc[8];
    #pragma unroll
    for (int r = 0; r < 8; ++r) acc[r] = make_float4(0.f, 0.f, 0.f, 0.f);

    for (int k0 = 0; k0 < K; k0 += 32) {
        __syncthreads();
        #pragma unroll
        for (int i = t; i < 512; i += 256) {
            int r = i >> 3, c4 = i & 7;
            int gr = row0 + r;
            float4 v = (gr < N_NODES) ? z4[(size_t)gr * ldz4 + (k0 >> 2) + c4]
                                      : make_float4(0, 0, 0, 0);
            *(float4*)&zS[r * 32 + c4 * 4] = v;
        }
        #pragma unroll
        for (int i = t; i < 1024; i += 256) wS[i] = W4[k0 * 32 + i];
        __syncthreads();
        #pragma unroll 8
        for (int kk = 0; kk < 32; ++kk) {
            float4 wv = wS[kk * 32 + tx];
            #pragma unroll
            for (int r = 0; r < 8; ++r) {
                float zv = zS[(ty * 8 + r) * 32 + kk];
                acc[r].x = fmaf(zv, wv.x, acc[r].x);
                acc[r].y = fmaf(zv, wv.y, acc[r].y);
                acc[r].z = fmaf(zv, wv.z, acc[r].z);
                acc[r].w = fmaf(zv, wv.w, acc[r].w);
            }
        }
    }

    float4* out4 = (float4*)out;
    const float4* bias4 = (const float4*)bias;
    float4 b = bias4[tx];
    #pragma unroll
    for (int r = 0; r < 8; ++r) {
        int gr = row0 + ty * 8 + r;
        if (gr >= N_NODES) continue;
        float4 o = acc[r];
        if (!init) {
            float4 prev = out4[(size_t)gr * 32 + tx];
            o.x += prev.x; o.y += prev.y; o.z += prev.z; o.w += prev.w;
        }
        if (final_) {
            o.x = fmaxf(o.x + b.x, 0.f);
            o.y = fmaxf(o.y + b.y, 0.f);
            o.z = fmaxf(o.z + b.z, 0.f);
            o.w = fmaxf(o.w + b.w, 0.f);
        }
        out4[(size_t)gr * 32 + tx] = o;
    }
}

// ---------------------------------------------------------------------------
extern "C" void kernel_launch(void* const* d_in, const int* in_sizes, int n_in,
                              void* d_out, int out_size, void* d_ws, size_t ws_size,
                              hipStream_t stream) {
    const float* x    = (const float*)d_in[0];
    const int*   rows = (const int*)d_in[1];
    const int*   cols = (const int*)d_in[2];
    const float* vals = (const float*)d_in[3];
    const float* kern = (const float*)d_in[4];
    const float* bias = (const float*)d_in[5];
    float* out = (float*)d_out;
    char* ws = (char*)d_ws;

    const int node_blocks = (N_NODES + 255) / 256;
    const int edge_blocks = (N_EDGES + 255) / 256;
    const int row_blocks  = (N_NODES + 3) / 4;
    const int gemm_blocks = (N_NODES + 63) / 64;

    // big path: z[N,384] + payload[3][E] + 3x {counts,row_start,fill} + bs
    const size_t Z_BYTES   = (size_t)N_NODES * 384 * 4;      // 76,800,000
    const size_t PAY_BYTES = (size_t)N_SUP * N_EDGES * 8;    // 19,200,000
    const size_t INT_BYTES = (size_t)N_SUP * NP_PAD * 4;     //    602,112
    const size_t NEED_BIG  = Z_BYTES + PAY_BYTES + 3 * INT_BYTES + 768;

    if (ws_size >= NEED_BIG) {
        float* z         = (float*)(ws);
        int2*  payload   = (int2*) (ws + Z_BYTES);
        int*   counts    = (int*)  (ws + Z_BYTES + PAY_BYTES);
        int*   row_start = (int*)  (ws + Z_BYTES + PAY_BYTES + INT_BYTES);
        int*   fillc     = (int*)  (ws + Z_BYTES + PAY_BYTES + 2 * INT_BYTES);
        int*   bs        = (int*)  (ws + Z_BYTES + PAY_BYTES + 3 * INT_BYTES);

        zero2_kernel<<<dim3(node_blocks, N_SUP), 256, 0, stream>>>(counts, fillc, NP_PAD);
        hist_kernel<<<dim3(edge_blocks, N_SUP), 256, 0, stream>>>(rows, 0, counts, NP_PAD);
        blocksum_kernel<<<dim3(NB_SCAN, N_SUP), 256, 0, stream>>>(counts, NP_PAD, bs);
        scan_bs_kernel<<<dim3(1, N_SUP), 64, 0, stream>>>(bs);
        scan_chunk_kernel<<<dim3(NB_SCAN, N_SUP), 256, 0, stream>>>(counts, NP_PAD, bs,
                                                                    row_start, NP_PAD);
        fill_kernel<<<dim3(edge_blocks, N_SUP), 256, 0, stream>>>(
            rows, cols, vals, 0, row_start, NP_PAD, fillc, NP_PAD, payload, N_EDGES);
        gather_kernel<<<dim3(row_blocks, N_SUP), 256, 0, stream>>>(
            (const float2*)x, payload, N_EDGES, row_start, NP_PAD, (float2*)z, 192);
        gemm_kernel<<<gemm_blocks, 256, 0, stream>>>(
            z, 96, 384, kern, bias, out, 1, 1);
    } else {
        // compact fallback (~32.6 MB): per-support, accumulate into out
        const size_t ZC_BYTES  = (size_t)N_NODES * FD * 4;   // 25,600,000
        const size_t PC_BYTES  = (size_t)N_EDGES * 8;        //  6,400,000
        float* zc        = (float*)(ws);
        int2*  payload   = (int2*) (ws + ZC_BYTES);
        int*   counts    = (int*)  (ws + ZC_BYTES + PC_BYTES);
        int*   row_start = (int*)  (ws + ZC_BYTES + PC_BYTES + NP_PAD * 4);
        int*   fillc     = (int*)  (ws + ZC_BYTES + PC_BYTES + 2 * NP_PAD * 4);
        int*   bs        = (int*)  (ws + ZC_BYTES + PC_BYTES + 3 * NP_PAD * 4);

        for (int k = 0; k < N_SUP; ++k) {
            zero2_kernel<<<dim3(node_blocks, 1), 256, 0, stream>>>(counts, fillc, 0);
            hist_kernel<<<dim3(edge_blocks, 1), 256, 0, stream>>>(rows, k, counts, 0);
            blocksum_kernel<<<dim3(NB_SCAN, 1), 256, 0, stream>>>(counts, 0, bs);
            scan_bs_kernel<<<dim3(1, 1), 64, 0, stream>>>(bs);
            scan_chunk_kernel<<<dim3(NB_SCAN, 1), 256, 0, stream>>>(counts, 0, bs,
                                                                    row_start, 0);
            fill_kernel<<<dim3(edge_blocks, 1), 256, 0, stream>>>(
                rows, cols, vals, k, row_start, 0, fillc, 0, payload, 0);
            gather_kernel<<<dim3(row_blocks, 1), 256, 0, stream>>>(
                (const float2*)x, payload, 0, row_start, 0, (float2*)zc, 64);
            gemm_kernel<<<gemm_blocks, 256, 0, stream>>>(
                zc, 32, 128, kern + (size_t)k * FD * FD, bias, out,
                k == 0 ? 1 : 0, k == N_SUP - 1 ? 1 : 0);
        }
    }
}

// Round 5
// 406.897 us; speedup vs baseline: 10.3542x; 1.3751x over previous
//
#include <hip/hip_runtime.h>

#define N_NODES 50000
#define N_EDGES 800000
#define N_SUP   3
#define FD      128
#define NP_PAD  50176        // per-support stride for row_start

#define NB      196          // buckets of 256 rows (covers 50176 rows)
#define RPB     256          // rows per bucket
#define EPB     3125         // edges per partition block (256 * 3125 = 800000 exact)
#define NBLK_E  256
#define K4_CAP  4864         // max edges per bucket (mean 4096, sigma 64 -> +12 sigma)

// ---------------------------------------------------------------------------
// K1: per-block LDS bucket histogram -> global ghist[sup][NB] (few atomics)
__global__ __launch_bounds__(256) void bhist_kernel(const int* __restrict__ rows,
                                                    int* __restrict__ ghist) {
    __shared__ int hist[NB];
    int t = threadIdx.x, y = blockIdx.y, blk = blockIdx.x;
    for (int i = t; i < NB; i += 256) hist[i] = 0;
    __syncthreads();
    size_t ebase = (size_t)y * N_EDGES + (size_t)blk * EPB;
    for (int i = t; i < EPB; i += 256)
        atomicAdd(&hist[rows[ebase + i] >> 8], 1);
    __syncthreads();
    for (int i = t; i < NB; i += 256)
        if (hist[i]) atomicAdd(&ghist[y * NB + i], hist[i]);
}

// ---------------------------------------------------------------------------
// K2: exclusive scan of ghist -> bucket_start[sup][NB+1], gcur[sup][NB]
__global__ __launch_bounds__(256) void bscan_kernel(const int* __restrict__ ghist,
                                                    int* __restrict__ bucket_start,
                                                    int* __restrict__ gcur) {
    __shared__ int s[256];
    int t = threadIdx.x, y = blockIdx.y;
    int cnt = (t < NB) ? ghist[y * NB + t] : 0;
    int val = cnt;
    s[t] = val; __syncthreads();
    for (int off = 1; off < 256; off <<= 1) {
        int v = (t >= off) ? s[t - off] : 0;
        __syncthreads();
        val += v; s[t] = val;
        __syncthreads();
    }
    int excl = val - cnt;
    if (t < NB) { bucket_start[y * (NB + 1) + t] = excl; gcur[y * NB + t] = excl; }
    if (t == NB - 1) bucket_start[y * (NB + 1) + NB] = val;   // = N_EDGES
}

// ---------------------------------------------------------------------------
// K3: partition edges into bucket-grouped tmp (int4 {row,col,valbits,0}).
// LDS counting sort by bucket; one global atomic per (block,bucket) run;
// global writes are contiguous runs (~16 edges) -> coalesced.
__global__ __launch_bounds__(256) void part_kernel(const int* __restrict__ rows,
                                                   const int* __restrict__ cols,
                                                   const float* __restrict__ vals,
                                                   int* __restrict__ gcur,
                                                   int4* __restrict__ tmp) {
    __shared__ int4     eS[EPB];          // 50,000 B
    __shared__ unsigned packed[EPB];      // 12,500 B
    __shared__ int hist[NB], lstart[NB], lcur[NB], gbase[NB];
    __shared__ int s[256];

    int t = threadIdx.x, y = blockIdx.y, blk = blockIdx.x;
    size_t ebase = (size_t)y * N_EDGES + (size_t)blk * EPB;

    for (int i = t; i < NB; i += 256) hist[i] = 0;
    __syncthreads();
    for (int i = t; i < EPB; i += 256) {
        int r = rows[ebase + i];
        int c = cols[ebase + i];
        float v = vals[ebase + i];
        eS[i] = make_int4(r, c, __float_as_int(v), 0);
        atomicAdd(&hist[r >> 8], 1);
    }
    __syncthreads();

    // exclusive scan hist -> lstart; reserve global run via one atomic
    int cnt = (t < NB) ? hist[t] : 0;
    int val = cnt;
    s[t] = val; __syncthreads();
    for (int off = 1; off < 256; off <<= 1) {
        int v = (t >= off) ? s[t - off] : 0;
        __syncthreads();
        val += v; s[t] = val;
        __syncthreads();
    }
    if (t < NB) {
        int excl = val - cnt;
        lstart[t] = excl; lcur[t] = excl;
        if (cnt > 0) gbase[t] = atomicAdd(&gcur[y * NB + t], cnt);
    }
    __syncthreads();

    // scatter local ranks
    for (int i = t; i < EPB; i += 256) {
        int b = eS[i].x >> 8;
        int pos = atomicAdd(&lcur[b], 1);
        packed[pos] = ((unsigned)b << 16) | (unsigned)i;
    }
    __syncthreads();

    // emit in locally-sorted order -> contiguous global runs per bucket
    for (int i = t; i < EPB; i += 256) {
        unsigned p = packed[i];
        int b = p >> 16, idx = p & 0xFFFF;
        tmp[(size_t)y * N_EDGES + gbase[b] + (i - lstart[b])] = eS[idx];
    }
}

// ---------------------------------------------------------------------------
// K4: one block per bucket: LDS sort by row -> payload (int2 {col,valbits})
// contiguous + exact row_start. All global reads/writes coalesced.
__global__ __launch_bounds__(256) void rowsort_kernel(const int4* __restrict__ tmp,
                                                      const int* __restrict__ bucket_start,
                                                      int2* __restrict__ payload,
                                                      int* __restrict__ row_start) {
    __shared__ int4     eS[K4_CAP];       // 77,824 B
    __shared__ unsigned packed[K4_CAP];   // 19,456 B
    __shared__ int rhist[RPB], rcur[RPB];
    __shared__ int s[256];

    int t = threadIdx.x, b = blockIdx.x, y = blockIdx.y;
    int start = bucket_start[y * (NB + 1) + b];
    int end   = bucket_start[y * (NB + 1) + b + 1];
    int cnt   = end - start;

    for (int i = t; i < RPB; i += 256) rhist[i] = 0;
    __syncthreads();
    const int4* src = tmp + (size_t)y * N_EDGES + start;
    for (int i = t; i < cnt; i += 256) {
        int4 e = src[i];
        eS[i] = e;
        atomicAdd(&rhist[e.x & 255], 1);
    }
    __syncthreads();

    // exclusive scan over 256 local rows (t == local row)
    int c0 = rhist[t];
    int val = c0;
    s[t] = val; __syncthreads();
    for (int off = 1; off < 256; off <<= 1) {
        int v = (t >= off) ? s[t - off] : 0;
        __syncthreads();
        val += v; s[t] = val;
        __syncthreads();
    }
    int excl = val - c0;
    rcur[t] = excl;
    int grow = b * RPB + t;
    if (grow < N_NODES) row_start[y * NP_PAD + grow] = start + excl;
    if (b == NB - 1 && t == 0) row_start[y * NP_PAD + N_NODES] = N_EDGES;
    __syncthreads();

    for (int i = t; i < cnt; i += 256) {
        int lr = eS[i].x & 255;
        int pos = atomicAdd(&rcur[lr], 1);
        packed[pos] = ((unsigned)lr << 16) | (unsigned)i;
    }
    __syncthreads();
    for (int i = t; i < cnt; i += 256) {
        int idx = packed[i] & 0xFFFF;
        int4 e = eS[idx];
        payload[(size_t)y * N_EDGES + start + i] = make_int2(e.y, e.z);
    }
}

// ---------------------------------------------------------------------------
// z[r, y*128 : +128] = sum_e val_e * x[col_e, :]  (unchanged from R4)
__global__ __launch_bounds__(256) void gather_kernel(const float2* __restrict__ x2,
                                                     const int2* __restrict__ payload,
                                                     int pstride,
                                                     const int* __restrict__ row_start,
                                                     int rstride,
                                                     float2* __restrict__ z2,
                                                     int ldz2) {
    int wid  = threadIdx.x >> 6;
    int lane = threadIdx.x & 63;
    int r = blockIdx.x * 4 + wid;
    if (r >= N_NODES) return;

    const int*  rs  = row_start + blockIdx.y * rstride;
    const int2* pay = payload + (size_t)blockIdx.y * pstride;
    int s = rs[r];
    int e = rs[r + 1];

    float2 a0 = {0.f, 0.f}, a1 = {0.f, 0.f}, a2 = {0.f, 0.f}, a3 = {0.f, 0.f};
    int i = s;
    for (; i + 4 <= e; i += 4) {
        int2 p0 = pay[i + 0], p1 = pay[i + 1], p2 = pay[i + 2], p3 = pay[i + 3];
        float2 g0 = x2[(size_t)p0.x * 64 + lane];
        float2 g1 = x2[(size_t)p1.x * 64 + lane];
        float2 g2 = x2[(size_t)p2.x * 64 + lane];
        float2 g3 = x2[(size_t)p3.x * 64 + lane];
        float v0 = __int_as_float(p0.y), v1 = __int_as_float(p1.y);
        float v2 = __int_as_float(p2.y), v3 = __int_as_float(p3.y);
        a0.x = fmaf(v0, g0.x, a0.x); a0.y = fmaf(v0, g0.y, a0.y);
        a1.x = fmaf(v1, g1.x, a1.x); a1.y = fmaf(v1, g1.y, a1.y);
        a2.x = fmaf(v2, g2.x, a2.x); a2.y = fmaf(v2, g2.y, a2.y);
        a3.x = fmaf(v3, g3.x, a3.x); a3.y = fmaf(v3, g3.y, a3.y);
    }
    for (; i < e; ++i) {
        int2 p = pay[i];
        float v = __int_as_float(p.y);
        float2 g = x2[(size_t)p.x * 64 + lane];
        a0.x = fmaf(v, g.x, a0.x); a0.y = fmaf(v, g.y, a0.y);
    }
    float2 acc = make_float2((a0.x + a1.x) + (a2.x + a3.x),
                             (a0.y + a1.y) + (a2.y + a3.y));
    z2[(size_t)r * ldz2 + blockIdx.y * 64 + lane] = acc;
}

// ---------------------------------------------------------------------------
// out[64-row tile,128] = relu(z[tile,384] @ W[384,128] + bias)  (unchanged)
__global__ __launch_bounds__(256) void gemm_kernel(const float* __restrict__ z,
                                                   int ldz4, int K,
                                                   const float* __restrict__ W,
                                                   const float* __restrict__ bias,
                                                   float* __restrict__ out,
                                                   int init, int final_) {
    __shared__ float  zS[64 * 32];
    __shared__ float4 wS[32 * 32];

    const int t    = threadIdx.x;
    const int row0 = blockIdx.x * 64;
    const int tx = t & 31;
    const int ty = t >> 5;
    const float4* z4 = (const float4*)z;
    const float4* W4 = (const float4*)W;

    float4 acc[8];
    #pragma unroll
    for (int r = 0; r < 8; ++r) acc[r] = make_float4(0.f, 0.f, 0.f, 0.f);

    for (int k0 = 0; k0 < K; k0 += 32) {
        __syncthreads();
        #pragma unroll
        for (int i = t; i < 512; i += 256) {
            int r = i >> 3, c4 = i & 7;
            int gr = row0 + r;
            float4 v = (gr < N_NODES) ? z4[(size_t)gr * ldz4 + (k0 >> 2) + c4]
                                      : make_float4(0, 0, 0, 0);
            *(float4*)&zS[r * 32 + c4 * 4] = v;
        }
        #pragma unroll
        for (int i = t; i < 1024; i += 256) wS[i] = W4[k0 * 32 + i];
        __syncthreads();
        #pragma unroll 8
        for (int kk = 0; kk < 32; ++kk) {
            float4 wv = wS[kk * 32 + tx];
            #pragma unroll
            for (int r = 0; r < 8; ++r) {
                float zv = zS[(ty * 8 + r) * 32 + kk];
                acc[r].x = fmaf(zv, wv.x, acc[r].x);
                acc[r].y = fmaf(zv, wv.y, acc[r].y);
                acc[r].z = fmaf(zv, wv.z, acc[r].z);
                acc[r].w = fmaf(zv, wv.w, acc[r].w);
            }
        }
    }

    float4* out4 = (float4*)out;
    const float4* bias4 = (const float4*)bias;
    float4 b = bias4[tx];
    #pragma unroll
    for (int r = 0; r < 8; ++r) {
        int gr = row0 + ty * 8 + r;
        if (gr >= N_NODES) continue;
        float4 o = acc[r];
        if (!init) {
            float4 prev = out4[(size_t)gr * 32 + tx];
            o.x += prev.x; o.y += prev.y; o.z += prev.z; o.w += prev.w;
        }
        if (final_) {
            o.x = fmaxf(o.x + b.x, 0.f);
            o.y = fmaxf(o.y + b.y, 0.f);
            o.z = fmaxf(o.z + b.z, 0.f);
            o.w = fmaxf(o.w + b.w, 0.f);
        }
        out4[(size_t)gr * 32 + tx] = o;
    }
}

// ---------------------------------------------------------------------------
extern "C" void kernel_launch(void* const* d_in, const int* in_sizes, int n_in,
                              void* d_out, int out_size, void* d_ws, size_t ws_size,
                              hipStream_t stream) {
    const float* x    = (const float*)d_in[0];
    const int*   rows = (const int*)d_in[1];
    const int*   cols = (const int*)d_in[2];
    const float* vals = (const float*)d_in[3];
    const float* kern = (const float*)d_in[4];
    const float* bias = (const float*)d_in[5];
    float* out = (float*)d_out;
    char* ws = (char*)d_ws;

    // ws layout (96.6 MB total; ws proven >= 97.8 MB by R4 big-path run):
    //   [0, 76.8M)  z [N,384] f32 -- first 38.4M doubles as tmp int4 (dead
    //               before gather writes z; same-stream ordering)
    //   [76.8M, +19.2M)  payload int2, stride N_EDGES per support
    //   [96.0M, +602K)   row_start, stride NP_PAD per support
    //   then ghist / gcur / bucket_start (few KB)
    const size_t OFF_Z    = 0;
    const size_t OFF_PAY  = 76800000;
    const size_t OFF_RS   = OFF_PAY + (size_t)N_SUP * N_EDGES * 8;   // 96,000,000
    const size_t OFF_GH   = OFF_RS + (size_t)N_SUP * NP_PAD * 4;     // 96,602,112
    const size_t OFF_GC   = OFF_GH + 2368;
    const size_t OFF_BS   = OFF_GC + 2368;

    float* z            = (float*)(ws + OFF_Z);
    int4*  tmp          = (int4*) (ws + OFF_Z);       // overlaps z
    int2*  payload      = (int2*) (ws + OFF_PAY);
    int*   row_start    = (int*)  (ws + OFF_RS);
    int*   ghist        = (int*)  (ws + OFF_GH);
    int*   gcur         = (int*)  (ws + OFF_GC);
    int*   bucket_start = (int*)  (ws + OFF_BS);

    const int row_blocks  = (N_NODES + 3) / 4;
    const int gemm_blocks = (N_NODES + 63) / 64;

    hipMemsetAsync(ghist, 0, N_SUP * NB * 4, stream);
    bhist_kernel<<<dim3(NBLK_E, N_SUP), 256, 0, stream>>>(rows, ghist);
    bscan_kernel<<<dim3(1, N_SUP), 256, 0, stream>>>(ghist, bucket_start, gcur);
    part_kernel<<<dim3(NBLK_E, N_SUP), 256, 0, stream>>>(rows, cols, vals, gcur, tmp);
    rowsort_kernel<<<dim3(NB, N_SUP), 256, 0, stream>>>(tmp, bucket_start,
                                                        payload, row_start);
    gather_kernel<<<dim3(row_blocks, N_SUP), 256, 0, stream>>>(
        (const float2*)x, payload, N_EDGES, row_start, NP_PAD, (float2*)z, 192);
    gemm_kernel<<<gemm_blocks, 256, 0, stream>>>(
        z, 96, 384, kern, bias, out, 1, 1);
}

// Round 7
// 335.784 us; speedup vs baseline: 12.5470x; 1.2118x over previous
//
#include <hip/hip_runtime.h>

#define N_NODES 50000
#define N_EDGES 800000
#define N_SUP   3
#define FD      128
#define NP_PAD  50176        // per-support stride for row_start

#define NB      196          // buckets of 256 rows (covers 50176 rows)
#define RPB     256          // rows per bucket
#define EPB     3125         // edges per partition block (256 * 3125 = 800000)
#define NBLK_E  256
#define K4_CAP  4864         // max edges per bucket (mean 4096, +12 sigma)

// bf16 helpers (RTN)
__device__ __forceinline__ unsigned rtn_bf16(float f) {
    unsigned u = __float_as_uint(f);
    return (u + 0x7FFFu + ((u >> 16) & 1u)) >> 16;
}
__device__ __forceinline__ float bf_lo(unsigned g) { return __uint_as_float(g << 16); }
__device__ __forceinline__ float bf_hi(unsigned g) { return __uint_as_float(g & 0xFFFF0000u); }

// ---------------------------------------------------------------------------
// K0: x f32 [N,128] -> xb bf16 packed (uint2 = 4 feats per thread)
__global__ __launch_bounds__(256) void cvt_x_kernel(const float4* __restrict__ x4,
                                                    uint2* __restrict__ xb) {
    int i = blockIdx.x * 256 + threadIdx.x;
    if (i >= N_NODES * 32) return;
    float4 v = x4[i];
    xb[i] = make_uint2(rtn_bf16(v.x) | (rtn_bf16(v.y) << 16),
                       rtn_bf16(v.z) | (rtn_bf16(v.w) << 16));
}

// ---------------------------------------------------------------------------
// K1: per-block LDS bucket histogram -> global ghist[sup][NB]
__global__ __launch_bounds__(256) void bhist_kernel(const int* __restrict__ rows,
                                                    int* __restrict__ ghist) {
    __shared__ int hist[NB];
    int t = threadIdx.x, y = blockIdx.y, blk = blockIdx.x;
    for (int i = t; i < NB; i += 256) hist[i] = 0;
    __syncthreads();
    size_t ebase = (size_t)y * N_EDGES + (size_t)blk * EPB;
    for (int i = t; i < EPB; i += 256)
        atomicAdd(&hist[rows[ebase + i] >> 8], 1);
    __syncthreads();
    for (int i = t; i < NB; i += 256)
        if (hist[i]) atomicAdd(&ghist[y * NB + i], hist[i]);
}

// ---------------------------------------------------------------------------
// K2: exclusive scan of ghist -> bucket_start[sup][NB+1], gcur[sup][NB]
__global__ __launch_bounds__(256) void bscan_kernel(const int* __restrict__ ghist,
                                                    int* __restrict__ bucket_start,
                                                    int* __restrict__ gcur) {
    __shared__ int s[256];
    int t = threadIdx.x, y = blockIdx.y;
    int cnt = (t < NB) ? ghist[y * NB + t] : 0;
    int val = cnt;
    s[t] = val; __syncthreads();
    for (int off = 1; off < 256; off <<= 1) {
        int v = (t >= off) ? s[t - off] : 0;
        __syncthreads();
        val += v; s[t] = val;
        __syncthreads();
    }
    int excl = val - cnt;
    if (t < NB) { bucket_start[y * (NB + 1) + t] = excl; gcur[y * NB + t] = excl; }
    if (t == NB - 1) bucket_start[y * (NB + 1) + NB] = val;
}

// ---------------------------------------------------------------------------
// K3: partition edges into bucket-grouped tmp (int4 {row,col,valbits,0}).
__global__ __launch_bounds__(256) void part_kernel(const int* __restrict__ rows,
                                                   const int* __restrict__ cols,
                                                   const float* __restrict__ vals,
                                                   int* __restrict__ gcur,
                                                   int4* __restrict__ tmp) {
    __shared__ int4     eS[EPB];
    __shared__ unsigned packed[EPB];
    __shared__ int hist[NB], lstart[NB], lcur[NB], gbase[NB];
    __shared__ int s[256];

    int t = threadIdx.x, y = blockIdx.y, blk = blockIdx.x;
    size_t ebase = (size_t)y * N_EDGES + (size_t)blk * EPB;

    for (int i = t; i < NB; i += 256) hist[i] = 0;
    __syncthreads();
    for (int i = t; i < EPB; i += 256) {
        int r = rows[ebase + i];
        int c = cols[ebase + i];
        float v = vals[ebase + i];
        eS[i] = make_int4(r, c, __float_as_int(v), 0);
        atomicAdd(&hist[r >> 8], 1);
    }
    __syncthreads();

    int cnt = (t < NB) ? hist[t] : 0;
    int val = cnt;
    s[t] = val; __syncthreads();
    for (int off = 1; off < 256; off <<= 1) {
        int v = (t >= off) ? s[t - off] : 0;
        __syncthreads();
        val += v; s[t] = val;
        __syncthreads();
    }
    if (t < NB) {
        int excl = val - cnt;
        lstart[t] = excl; lcur[t] = excl;
        if (cnt > 0) gbase[t] = atomicAdd(&gcur[y * NB + t], cnt);
    }
    __syncthreads();

    for (int i = t; i < EPB; i += 256) {
        int b = eS[i].x >> 8;
        int pos = atomicAdd(&lcur[b], 1);
        packed[pos] = ((unsigned)b << 16) | (unsigned)i;
    }
    __syncthreads();

    for (int i = t; i < EPB; i += 256) {
        unsigned p = packed[i];
        int b = p >> 16, idx = p & 0xFFFF;
        tmp[(size_t)y * N_EDGES + gbase[b] + (i - lstart[b])] = eS[idx];
    }
}

// ---------------------------------------------------------------------------
// K4: one block per bucket: LDS sort by row -> payload int2 + exact row_start
__global__ __launch_bounds__(256) void rowsort_kernel(const int4* __restrict__ tmp,
                                                      const int* __restrict__ bucket_start,
                                                      int2* __restrict__ payload,
                                                      int* __restrict__ row_start) {
    __shared__ int4     eS[K4_CAP];
    __shared__ unsigned packed[K4_CAP];
    __shared__ int rhist[RPB], rcur[RPB];
    __shared__ int s[256];

    int t = threadIdx.x, b = blockIdx.x, y = blockIdx.y;
    int start = bucket_start[y * (NB + 1) + b];
    int end   = bucket_start[y * (NB + 1) + b + 1];
    int cnt   = end - start;

    for (int i = t; i < RPB; i += 256) rhist[i] = 0;
    __syncthreads();
    const int4* src = tmp + (size_t)y * N_EDGES + start;
    for (int i = t; i < cnt; i += 256) {
        int4 e = src[i];
        eS[i] = e;
        atomicAdd(&rhist[e.x & 255], 1);
    }
    __syncthreads();

    int c0 = rhist[t];
    int val = c0;
    s[t] = val; __syncthreads();
    for (int off = 1; off < 256; off <<= 1) {
        int v = (t >= off) ? s[t - off] : 0;
        __syncthreads();
        val += v; s[t] = val;
        __syncthreads();
    }
    int excl = val - c0;
    rcur[t] = excl;
    int grow = b * RPB + t;
    if (grow < N_NODES) row_start[y * NP_PAD + grow] = start + excl;
    if (b == NB - 1 && t == 0) row_start[y * NP_PAD + N_NODES] = N_EDGES;
    __syncthreads();

    for (int i = t; i < cnt; i += 256) {
        int lr = eS[i].x & 255;
        int pos = atomicAdd(&rcur[lr], 1);
        packed[pos] = ((unsigned)lr << 16) | (unsigned)i;
    }
    __syncthreads();
    for (int i = t; i < cnt; i += 256) {
        int idx = packed[i] & 0xFFFF;
        int4 e = eS[idx];
        payload[(size_t)y * N_EDGES + start + i] = make_int2(e.y, e.z);
    }
}

// ---------------------------------------------------------------------------
// Gather: zb[r, y*128:+128] (bf16) = sum_e val_e * xb[col_e, :]
// One wave per row; lane owns 2 feats (uint of 2 bf16); f32 accumulate;
// 8/4/1 unroll cascade for memory-level parallelism.
__global__ __launch_bounds__(256) void gather_kernel(const unsigned* __restrict__ xb,
                                                     const int2* __restrict__ payload,
                                                     int pstride,
                                                     const int* __restrict__ row_start,
                                                     int rstride,
                                                     unsigned* __restrict__ zb,
                                                     int ldzu) {
    int wid  = threadIdx.x >> 6;
    int lane = threadIdx.x & 63;
    int r = blockIdx.x * 4 + wid;
    if (r >= N_NODES) return;

    const int*  rs  = row_start + blockIdx.y * rstride;
    const int2* pay = payload + (size_t)blockIdx.y * pstride;
    int s = rs[r];
    int e = rs[r + 1];

    float2 a0 = {0.f, 0.f}, a1 = {0.f, 0.f}, a2 = {0.f, 0.f}, a3 = {0.f, 0.f};
    int i = s;
    for (; i + 8 <= e; i += 8) {
        int2 p0 = pay[i + 0], p1 = pay[i + 1], p2 = pay[i + 2], p3 = pay[i + 3];
        int2 p4 = pay[i + 4], p5 = pay[i + 5], p6 = pay[i + 6], p7 = pay[i + 7];
        unsigned g0 = xb[(size_t)p0.x * 64 + lane];
        unsigned g1 = xb[(size_t)p1.x * 64 + lane];
        unsigned g2 = xb[(size_t)p2.x * 64 + lane];
        unsigned g3 = xb[(size_t)p3.x * 64 + lane];
        unsigned g4 = xb[(size_t)p4.x * 64 + lane];
        unsigned g5 = xb[(size_t)p5.x * 64 + lane];
        unsigned g6 = xb[(size_t)p6.x * 64 + lane];
        unsigned g7 = xb[(size_t)p7.x * 64 + lane];
        float v0 = __int_as_float(p0.y), v1 = __int_as_float(p1.y);
        float v2 = __int_as_float(p2.y), v3 = __int_as_float(p3.y);
        float v4 = __int_as_float(p4.y), v5 = __int_as_float(p5.y);
        float v6 = __int_as_float(p6.y), v7 = __int_as_float(p7.y);
        a0.x = fmaf(v0, bf_lo(g0), a0.x); a0.y = fmaf(v0, bf_hi(g0), a0.y);
        a1.x = fmaf(v1, bf_lo(g1), a1.x); a1.y = fmaf(v1, bf_hi(g1), a1.y);
        a2.x = fmaf(v2, bf_lo(g2), a2.x); a2.y = fmaf(v2, bf_hi(g2), a2.y);
        a3.x = fmaf(v3, bf_lo(g3), a3.x); a3.y = fmaf(v3, bf_hi(g3), a3.y);
        a0.x = fmaf(v4, bf_lo(g4), a0.x); a0.y = fmaf(v4, bf_hi(g4), a0.y);
        a1.x = fmaf(v5, bf_lo(g5), a1.x); a1.y = fmaf(v5, bf_hi(g5), a1.y);
        a2.x = fmaf(v6, bf_lo(g6), a2.x); a2.y = fmaf(v6, bf_hi(g6), a2.y);
        a3.x = fmaf(v7, bf_lo(g7), a3.x); a3.y = fmaf(v7, bf_hi(g7), a3.y);
    }
    for (; i + 4 <= e; i += 4) {
        int2 p0 = pay[i + 0], p1 = pay[i + 1], p2 = pay[i + 2], p3 = pay[i + 3];
        unsigned g0 = xb[(size_t)p0.x * 64 + lane];
        unsigned g1 = xb[(size_t)p1.x * 64 + lane];
        unsigned g2 = xb[(size_t)p2.x * 64 + lane];
        unsigned g3 = xb[(size_t)p3.x * 64 + lane];
        float v0 = __int_as_float(p0.y), v1 = __int_as_float(p1.y);
        float v2 = __int_as_float(p2.y), v3 = __int_as_float(p3.y);
        a0.x = fmaf(v0, bf_lo(g0), a0.x); a0.y = fmaf(v0, bf_hi(g0), a0.y);
        a1.x = fmaf(v1, bf_lo(g1), a1.x); a1.y = fmaf(v1, bf_hi(g1), a1.y);
        a2.x = fmaf(v2, bf_lo(g2), a2.x); a2.y = fmaf(v2, bf_hi(g2), a2.y);
        a3.x = fmaf(v3, bf_lo(g3), a3.x); a3.y = fmaf(v3, bf_hi(g3), a3.y);
    }
    for (; i < e; ++i) {
        int2 p = pay[i];
        float v = __int_as_float(p.y);
        unsigned g = xb[(size_t)p.x * 64 + lane];
        a0.x = fmaf(v, bf_lo(g), a0.x); a0.y = fmaf(v, bf_hi(g), a0.y);
    }
    float ax = (a0.x + a1.x) + (a2.x + a3.x);
    float ay = (a0.y + a1.y) + (a2.y + a3.y);
    zb[(size_t)r * ldzu + blockIdx.y * 64 + lane] =
        rtn_bf16(ax) | (rtn_bf16(ay) << 16);
}

// ---------------------------------------------------------------------------
// out[64-row tile,128] = relu(zb[tile,384](bf16) @ W[384,128](f32) + bias)
__global__ __launch_bounds__(256) void gemm_kernel(const uint4* __restrict__ zu4,
                                                   const float* __restrict__ W,
                                                   const float* __restrict__ bias,
                                                   float* __restrict__ out) {
    __shared__ float  zS[64 * 32];
    __shared__ float4 wS[32 * 32];

    const int t    = threadIdx.x;
    const int row0 = blockIdx.x * 64;
    const int tx = t & 31;
    const int ty = t >> 5;
    const float4* W4 = (const float4*)W;

    float4 acc[8];
    #pragma unroll
    for (int r = 0; r < 8; ++r) acc[r] = make_float4(0.f, 0.f, 0.f, 0.f);

    for (int k0 = 0; k0 < 384; k0 += 32) {
        __syncthreads();
        {   // stage 64 rows x 32 cols of z (bf16 -> f32): 256 uint4, one per thread
            int r = t >> 2, c8 = t & 3;
            int gr = row0 + r;
            uint4 v = (gr < N_NODES) ? zu4[(size_t)gr * 48 + (k0 >> 3) + c8]
                                     : make_uint4(0, 0, 0, 0);
            float* d = &zS[r * 32 + c8 * 8];
            d[0] = bf_lo(v.x); d[1] = bf_hi(v.x);
            d[2] = bf_lo(v.y); d[3] = bf_hi(v.y);
            d[4] = bf_lo(v.z); d[5] = bf_hi(v.z);
            d[6] = bf_lo(v.w); d[7] = bf_hi(v.w);
        }
        #pragma unroll
        for (int i = t; i < 1024; i += 256) wS[i] = W4[k0 * 32 + i];
        __syncthreads();
        #pragma unroll 8
        for (int kk = 0; kk < 32; ++kk) {
            float4 wv = wS[kk * 32 + tx];
            #pragma unroll
            for (int r = 0; r < 8; ++r) {
                float zv = zS[(ty * 8 + r) * 32 + kk];
                acc[r].x = fmaf(zv, wv.x, acc[r].x);
                acc[r].y = fmaf(zv, wv.y, acc[r].y);
                acc[r].z = fmaf(zv, wv.z, acc[r].z);
                acc[r].w = fmaf(zv, wv.w, acc[r].w);
            }
        }
    }

    float4* out4 = (float4*)out;
    const float4* bias4 = (const float4*)bias;
    float4 b = bias4[tx];
    #pragma unroll
    for (int r = 0; r < 8; ++r) {
        int gr = row0 + ty * 8 + r;
        if (gr >= N_NODES) continue;
        float4 o = acc[r];
        o.x = fmaxf(o.x + b.x, 0.f);
        o.y = fmaxf(o.y + b.y, 0.f);
        o.z = fmaxf(o.z + b.z, 0.f);
        o.w = fmaxf(o.w + b.w, 0.f);
        out4[(size_t)gr * 32 + tx] = o;
    }
}

// ---------------------------------------------------------------------------
extern "C" void kernel_launch(void* const* d_in, const int* in_sizes, int n_in,
                              void* d_out, int out_size, void* d_ws, size_t ws_size,
                              hipStream_t stream) {
    const float* x    = (const float*)d_in[0];
    const int*   rows = (const int*)d_in[1];
    const int*   cols = (const int*)d_in[2];
    const float* vals = (const float*)d_in[3];
    const float* kern = (const float*)d_in[4];
    const float* bias = (const float*)d_in[5];
    float* out = (float*)d_out;
    char* ws = (char*)d_ws;

    // ws layout (~71 MB; big path proven >= 96.6 MB in R4/R5):
    //   [0, 38.4M)   zb bf16 [N,384] -- doubles as tmp int4 (exact size match;
    //                tmp dead before gather writes zb, same-stream ordering)
    //   [38.4M, +12.8M)  xb bf16 [N,128]
    //   [51.2M, +19.2M)  payload int2, stride N_EDGES per support
    //   [70.4M, +602K)   row_start, stride NP_PAD per support
    //   then ghist / gcur / bucket_start (few KB)
    const size_t OFF_ZB  = 0;
    const size_t OFF_XB  = 38400000;
    const size_t OFF_PAY = OFF_XB + 12800000;                       // 51,200,000
    const size_t OFF_RS  = OFF_PAY + (size_t)N_SUP * N_EDGES * 8;   // 70,400,000
    const size_t OFF_GH  = OFF_RS + (size_t)N_SUP * NP_PAD * 4;     // 71,002,112
    const size_t OFF_GC  = OFF_GH + 2368;
    const size_t OFF_BS  = OFF_GC + 2368;

    unsigned* zb           = (unsigned*)(ws + OFF_ZB);
    int4*     tmp          = (int4*)    (ws + OFF_ZB);   // overlaps zb
    unsigned* xbuf         = (unsigned*)(ws + OFF_XB);
    int2*     payload      = (int2*)    (ws + OFF_PAY);
    int*      row_start    = (int*)     (ws + OFF_RS);
    int*      ghist        = (int*)     (ws + OFF_GH);
    int*      gcur         = (int*)     (ws + OFF_GC);
    int*      bucket_start = (int*)     (ws + OFF_BS);

    const int row_blocks  = (N_NODES + 3) / 4;
    const int gemm_blocks = (N_NODES + 63) / 64;

    hipMemsetAsync(ghist, 0, N_SUP * NB * 4, stream);
    cvt_x_kernel<<<(N_NODES * 32 + 255) / 256, 256, 0, stream>>>(
        (const float4*)x, (uint2*)xbuf);
    bhist_kernel<<<dim3(NBLK_E, N_SUP), 256, 0, stream>>>(rows, ghist);
    bscan_kernel<<<dim3(1, N_SUP), 256, 0, stream>>>(ghist, bucket_start, gcur);
    part_kernel<<<dim3(NBLK_E, N_SUP), 256, 0, stream>>>(rows, cols, vals, gcur, tmp);
    rowsort_kernel<<<dim3(NB, N_SUP), 256, 0, stream>>>(tmp, bucket_start,
                                                        payload, row_start);
    gather_kernel<<<dim3(row_blocks, N_SUP), 256, 0, stream>>>(
        xbuf, payload, N_EDGES, row_start, NP_PAD, zb, 192);
    gemm_kernel<<<gemm_blocks, 256, 0, stream>>>(
        (const uint4*)zb, kern, bias, out);
}

// Round 8
// 282.182 us; speedup vs baseline: 14.9304x; 1.1900x over previous
//
#include <hip/hip_runtime.h>

#define N_NODES 50000
#define N_EDGES 800000
#define N_SUP   3
#define FD      128
#define NP_PAD  50176        // per-support stride for row_start

#define NB      196          // buckets of 256 rows
#define RPB     256
#define EPB     3125         // 256 * 3125 = 800000
#define NBLK_E  256

typedef __attribute__((ext_vector_type(8))) short bf16x8;
typedef __attribute__((ext_vector_type(4))) float f32x4;

// bf16 helpers (RTN)
__device__ __forceinline__ unsigned rtn_bf16(float f) {
    unsigned u = __float_as_uint(f);
    return (u + 0x7FFFu + ((u >> 16) & 1u)) >> 16;
}
__device__ __forceinline__ float bf_lo(unsigned g) { return __uint_as_float(g << 16); }
__device__ __forceinline__ float bf_hi(unsigned g) { return __uint_as_float(g & 0xFFFF0000u); }

// ---------------------------------------------------------------------------
// K0a: x f32 [N,128] -> xb bf16 packed
__global__ __launch_bounds__(256) void cvt_x_kernel(const float4* __restrict__ x4,
                                                    uint2* __restrict__ xb) {
    int i = blockIdx.x * 256 + threadIdx.x;
    if (i >= N_NODES * 32) return;
    float4 v = x4[i];
    xb[i] = make_uint2(rtn_bf16(v.x) | (rtn_bf16(v.y) << 16),
                       rtn_bf16(v.z) | (rtn_bf16(v.w) << 16));
}

// ---------------------------------------------------------------------------
// K0b: W f32 [384,128] -> WT bf16 [col 128][k 384], quad-swizzled within each
// 4-quad (64 B) group: stored quad p holds logical quad (p&~3)|((p&3)^((col>>1)&3)).
__global__ __launch_bounds__(256) void cvt_w_kernel(const float* __restrict__ W,
                                                    uint4* __restrict__ wtb) {
    int tid = blockIdx.x * 256 + threadIdx.x;
    if (tid >= 128 * 48) return;
    int col = tid / 48, p = tid % 48;
    int qlog = (p & ~3) | ((p & 3) ^ ((col >> 1) & 3));
    int k0 = qlog * 8;
    unsigned w0 = rtn_bf16(W[(k0 + 0) * 128 + col]) | (rtn_bf16(W[(k0 + 1) * 128 + col]) << 16);
    unsigned w1 = rtn_bf16(W[(k0 + 2) * 128 + col]) | (rtn_bf16(W[(k0 + 3) * 128 + col]) << 16);
    unsigned w2 = rtn_bf16(W[(k0 + 4) * 128 + col]) | (rtn_bf16(W[(k0 + 5) * 128 + col]) << 16);
    unsigned w3 = rtn_bf16(W[(k0 + 6) * 128 + col]) | (rtn_bf16(W[(k0 + 7) * 128 + col]) << 16);
    wtb[col * 48 + p] = make_uint4(w0, w1, w2, w3);
}

// ---------------------------------------------------------------------------
// K1: per-block LDS bucket histogram -> ghist[sup][NB]
__global__ __launch_bounds__(256) void bhist_kernel(const int* __restrict__ rows,
                                                    int* __restrict__ ghist) {
    __shared__ int hist[NB];
    int t = threadIdx.x, y = blockIdx.y, blk = blockIdx.x;
    for (int i = t; i < NB; i += 256) hist[i] = 0;
    __syncthreads();
    size_t ebase = (size_t)y * N_EDGES + (size_t)blk * EPB;
    for (int i = t; i < EPB; i += 256)
        atomicAdd(&hist[rows[ebase + i] >> 8], 1);
    __syncthreads();
    for (int i = t; i < NB; i += 256)
        if (hist[i]) atomicAdd(&ghist[y * NB + i], hist[i]);
}

// ---------------------------------------------------------------------------
// K2: exclusive scan -> bucket_start[sup][NB+1], gcur[sup][NB]
__global__ __launch_bounds__(256) void bscan_kernel(const int* __restrict__ ghist,
                                                    int* __restrict__ bucket_start,
                                                    int* __restrict__ gcur) {
    __shared__ int s[256];
    int t = threadIdx.x, y = blockIdx.y;
    int cnt = (t < NB) ? ghist[y * NB + t] : 0;
    int val = cnt;
    s[t] = val; __syncthreads();
    for (int off = 1; off < 256; off <<= 1) {
        int v = (t >= off) ? s[t - off] : 0;
        __syncthreads();
        val += v; s[t] = val;
        __syncthreads();
    }
    int excl = val - cnt;
    if (t < NB) { bucket_start[y * (NB + 1) + t] = excl; gcur[y * NB + t] = excl; }
    if (t == NB - 1) bucket_start[y * (NB + 1) + NB] = val;
}

// ---------------------------------------------------------------------------
// K3: partition edges into bucket-grouped tmp (int4 {row,col,valbits,0})
__global__ __launch_bounds__(256) void part_kernel(const int* __restrict__ rows,
                                                   const int* __restrict__ cols,
                                                   const float* __restrict__ vals,
                                                   int* __restrict__ gcur,
                                                   int4* __restrict__ tmp) {
    __shared__ int4     eS[EPB];
    __shared__ unsigned packed[EPB];
    __shared__ int hist[NB], lstart[NB], lcur[NB], gbase[NB];
    __shared__ int s[256];

    int t = threadIdx.x, y = blockIdx.y, blk = blockIdx.x;
    size_t ebase = (size_t)y * N_EDGES + (size_t)blk * EPB;

    for (int i = t; i < NB; i += 256) hist[i] = 0;
    __syncthreads();
    for (int i = t; i < EPB; i += 256) {
        int r = rows[ebase + i];
        int c = cols[ebase + i];
        float v = vals[ebase + i];
        eS[i] = make_int4(r, c, __float_as_int(v), 0);
        atomicAdd(&hist[r >> 8], 1);
    }
    __syncthreads();

    int cnt = (t < NB) ? hist[t] : 0;
    int val = cnt;
    s[t] = val; __syncthreads();
    for (int off = 1; off < 256; off <<= 1) {
        int v = (t >= off) ? s[t - off] : 0;
        __syncthreads();
        val += v; s[t] = val;
        __syncthreads();
    }
    if (t < NB) {
        int excl = val - cnt;
        lstart[t] = excl; lcur[t] = excl;
        if (cnt > 0) gbase[t] = atomicAdd(&gcur[y * NB + t], cnt);
    }
    __syncthreads();

    for (int i = t; i < EPB; i += 256) {
        int b = eS[i].x >> 8;
        int pos = atomicAdd(&lcur[b], 1);
        packed[pos] = ((unsigned)b << 16) | (unsigned)i;
    }
    __syncthreads();

    for (int i = t; i < EPB; i += 256) {
        unsigned p = packed[i];
        int b = p >> 16, idx = p & 0xFFFF;
        tmp[(size_t)y * N_EDGES + gbase[b] + (i - lstart[b])] = eS[idx];
    }
}

// ---------------------------------------------------------------------------
// K4: two-pass per-bucket row sort (3 KB LDS -> high occupancy):
// pass1 histogram rows, scan; pass2 re-read tmp, write payload at rank.
__global__ __launch_bounds__(256) void rowsort_kernel(const int4* __restrict__ tmp,
                                                      const int* __restrict__ bucket_start,
                                                      int2* __restrict__ payload,
                                                      int* __restrict__ row_start) {
    __shared__ int rhist[RPB], rcur[RPB];
    __shared__ int s[256];

    int t = threadIdx.x, b = blockIdx.x, y = blockIdx.y;
    int start = bucket_start[y * (NB + 1) + b];
    int end   = bucket_start[y * (NB + 1) + b + 1];
    int cnt   = end - start;

    rhist[t] = 0;
    __syncthreads();
    const int4* src = tmp + (size_t)y * N_EDGES + start;
    for (int i = t; i < cnt; i += 256)
        atomicAdd(&rhist[src[i].x & 255], 1);
    __syncthreads();

    int c0 = rhist[t];
    int val = c0;
    s[t] = val; __syncthreads();
    for (int off = 1; off < 256; off <<= 1) {
        int v = (t >= off) ? s[t - off] : 0;
        __syncthreads();
        val += v; s[t] = val;
        __syncthreads();
    }
    int excl = val - c0;
    rcur[t] = excl;
    int grow = b * RPB + t;
    if (grow < N_NODES) row_start[y * NP_PAD + grow] = start + excl;
    if (b == NB - 1 && t == 0) row_start[y * NP_PAD + N_NODES] = N_EDGES;
    __syncthreads();

    int2* dst = payload + (size_t)y * N_EDGES + start;
    for (int i = t; i < cnt; i += 256) {
        int4 e = src[i];
        int pos = atomicAdd(&rcur[e.x & 255], 1);
        dst[pos] = make_int2(e.y, e.z);
    }
}

// ---------------------------------------------------------------------------
// Gather: zb[r, y*128:+128] (bf16) = sum_e val_e * xb[col_e, :]
// Store index quad-swizzled by ((r>>1)&3) so the MFMA GEMM can use
// global_load_lds with a linear LDS destination (pre-swizzled-source trick).
__global__ __launch_bounds__(256) void gather_kernel(const unsigned* __restrict__ xb,
                                                     const int2* __restrict__ payload,
                                                     const int* __restrict__ row_start,
                                                     unsigned* __restrict__ zb) {
    int wid  = threadIdx.x >> 6;
    int lane = threadIdx.x & 63;
    int r = blockIdx.x * 4 + wid;
    if (r >= N_NODES) return;

    const int*  rs  = row_start + blockIdx.y * NP_PAD;
    const int2* pay = payload + (size_t)blockIdx.y * N_EDGES;
    int s = rs[r];
    int e = rs[r + 1];

    float2 a0 = {0.f, 0.f}, a1 = {0.f, 0.f}, a2 = {0.f, 0.f}, a3 = {0.f, 0.f};
    int i = s;
    for (; i + 8 <= e; i += 8) {
        int2 p0 = pay[i + 0], p1 = pay[i + 1], p2 = pay[i + 2], p3 = pay[i + 3];
        int2 p4 = pay[i + 4], p5 = pay[i + 5], p6 = pay[i + 6], p7 = pay[i + 7];
        unsigned g0 = xb[(size_t)p0.x * 64 + lane];
        unsigned g1 = xb[(size_t)p1.x * 64 + lane];
        unsigned g2 = xb[(size_t)p2.x * 64 + lane];
        unsigned g3 = xb[(size_t)p3.x * 64 + lane];
        unsigned g4 = xb[(size_t)p4.x * 64 + lane];
        unsigned g5 = xb[(size_t)p5.x * 64 + lane];
        unsigned g6 = xb[(size_t)p6.x * 64 + lane];
        unsigned g7 = xb[(size_t)p7.x * 64 + lane];
        float v0 = __int_as_float(p0.y), v1 = __int_as_float(p1.y);
        float v2 = __int_as_float(p2.y), v3 = __int_as_float(p3.y);
        float v4 = __int_as_float(p4.y), v5 = __int_as_float(p5.y);
        float v6 = __int_as_float(p6.y), v7 = __int_as_float(p7.y);
        a0.x = fmaf(v0, bf_lo(g0), a0.x); a0.y = fmaf(v0, bf_hi(g0), a0.y);
        a1.x = fmaf(v1, bf_lo(g1), a1.x); a1.y = fmaf(v1, bf_hi(g1), a1.y);
        a2.x = fmaf(v2, bf_lo(g2), a2.x); a2.y = fmaf(v2, bf_hi(g2), a2.y);
        a3.x = fmaf(v3, bf_lo(g3), a3.x); a3.y = fmaf(v3, bf_hi(g3), a3.y);
        a0.x = fmaf(v4, bf_lo(g4), a0.x); a0.y = fmaf(v4, bf_hi(g4), a0.y);
        a1.x = fmaf(v5, bf_lo(g5), a1.x); a1.y = fmaf(v5, bf_hi(g5), a1.y);
        a2.x = fmaf(v6, bf_lo(g6), a2.x); a2.y = fmaf(v6, bf_hi(g6), a2.y);
        a3.x = fmaf(v7, bf_lo(g7), a3.x); a3.y = fmaf(v7, bf_hi(g7), a3.y);
    }
    for (; i + 4 <= e; i += 4) {
        int2 p0 = pay[i + 0], p1 = pay[i + 1], p2 = pay[i + 2], p3 = pay[i + 3];
        unsigned g0 = xb[(size_t)p0.x * 64 + lane];
        unsigned g1 = xb[(size_t)p1.x * 64 + lane];
        unsigned g2 = xb[(size_t)p2.x * 64 + lane];
        unsigned g3 = xb[(size_t)p3.x * 64 + lane];
        float v0 = __int_as_float(p0.y), v1 = __int_as_float(p1.y);
        float v2 = __int_as_float(p2.y), v3 = __int_as_float(p3.y);
        a0.x = fmaf(v0, bf_lo(g0), a0.x); a0.y = fmaf(v0, bf_hi(g0), a0.y);
        a1.x = fmaf(v1, bf_lo(g1), a1.x); a1.y = fmaf(v1, bf_hi(g1), a1.y);
        a2.x = fmaf(v2, bf_lo(g2), a2.x); a2.y = fmaf(v2, bf_hi(g2), a2.y);
        a3.x = fmaf(v3, bf_lo(g3), a3.x); a3.y = fmaf(v3, bf_hi(g3), a3.y);
    }
    for (; i < e; ++i) {
        int2 p = pay[i];
        float v = __int_as_float(p.y);
        unsigned g = xb[(size_t)p.x * 64 + lane];
        a0.x = fmaf(v, bf_lo(g), a0.x); a0.y = fmaf(v, bf_hi(g), a0.y);
    }
    float ax = (a0.x + a1.x) + (a2.x + a3.x);
    float ay = (a0.y + a1.y) + (a2.y + a3.y);
    unsigned u = (blockIdx.y << 6) + lane;                 // u32 index in row
    unsigned usw = u ^ (((unsigned)(r >> 1) & 3u) << 2);   // quad swizzle
    zb[(size_t)r * 192 + usw] = rtn_bf16(ax) | (rtn_bf16(ay) << 16);
}

// ---------------------------------------------------------------------------
// MFMA GEMM: out[32-row tile, 128] = relu(z[tile,384]bf16 @ W[384,128]bf16 + bias)
// 4 waves: wave wv -> cols wv*32..+32; per wave 2x2 frags of 16x16.
// A/B staged via global_load_lds (linear LDS dest, sources pre-swizzled).
__global__ __launch_bounds__(256) void mfma_gemm_kernel(const char* __restrict__ zb_sw,
                                                        const char* __restrict__ wtb_sw,
                                                        const float* __restrict__ bias,
                                                        float* __restrict__ out) {
    __shared__ __align__(16) char zS[2048];    // 32 rows x 32 k bf16
    __shared__ __align__(16) char wS[8192];    // 128 cols x 32 k bf16

    const int t    = threadIdx.x;
    const int lane = t & 63;
    const int wv   = t >> 6;
    const int row0 = blockIdx.x * 32;
    const int m = lane >> 4;    // quad index / C-row group
    const int n = lane & 15;

    // LDS frag read offsets (xor-swizzled to match pre-swizzled sources)
    const int ar0   = n;
    const int ar1   = 16 + n;
    const int aoff0 = ar0 * 64 + ((m ^ ((ar0 >> 1) & 3)) * 16);
    const int aoff1 = ar1 * 64 + ((m ^ ((ar1 >> 1) & 3)) * 16);
    const int col0  = wv * 32 + n;
    const int col1  = col0 + 16;
    const int boff0 = col0 * 64 + ((m ^ ((col0 >> 1) & 3)) * 16);
    const int boff1 = col1 * 64 + ((m ^ ((col1 >> 1) & 3)) * 16);

    f32x4 acc00 = {0.f, 0.f, 0.f, 0.f};
    f32x4 acc01 = acc00, acc10 = acc00, acc11 = acc00;

    for (int ks = 0; ks < 12; ++ks) {
        __syncthreads();   // previous frag reads done; LDS free
        if (t < 128) {     // A: 32 rows x 4 quads (waves 0-1)
            const char* asrc = zb_sw + (size_t)(row0 + (t >> 2)) * 768 + ks * 64 + (t & 3) * 16;
            __builtin_amdgcn_global_load_lds(
                (const __attribute__((address_space(1))) void*)asrc,
                (__attribute__((address_space(3))) void*)(zS + t * 16), 16, 0, 0);
        }
        {                  // B: 128 cols x 4 quads, 2 per thread
            const char* bsrc0 = wtb_sw + (t >> 2) * 768 + ks * 64 + (t & 3) * 16;
            __builtin_amdgcn_global_load_lds(
                (const __attribute__((address_space(1))) void*)bsrc0,
                (__attribute__((address_space(3))) void*)(wS + t * 16), 16, 0, 0);
            int i = t + 256;
            const char* bsrc1 = wtb_sw + (i >> 2) * 768 + ks * 64 + (i & 3) * 16;
            __builtin_amdgcn_global_load_lds(
                (const __attribute__((address_space(1))) void*)bsrc1,
                (__attribute__((address_space(3))) void*)(wS + i * 16), 16, 0, 0);
        }
        __syncthreads();   // compiler drains vmcnt before barrier

        bf16x8 a0 = *(const bf16x8*)(zS + aoff0);
        bf16x8 a1 = *(const bf16x8*)(zS + aoff1);
        bf16x8 b0 = *(const bf16x8*)(wS + boff0);
        bf16x8 b1 = *(const bf16x8*)(wS + boff1);
        acc00 = __builtin_amdgcn_mfma_f32_16x16x32_bf16(a0, b0, acc00, 0, 0, 0);
        acc01 = __builtin_amdgcn_mfma_f32_16x16x32_bf16(a0, b1, acc01, 0, 0, 0);
        acc10 = __builtin_amdgcn_mfma_f32_16x16x32_bf16(a1, b0, acc10, 0, 0, 0);
        acc11 = __builtin_amdgcn_mfma_f32_16x16x32_bf16(a1, b1, acc11, 0, 0, 0);
    }

    float bv0 = bias[col0], bv1 = bias[col1];
    #pragma unroll
    for (int j = 0; j < 4; ++j) {
        int r0 = row0 + m * 4 + j;     // C/D: row=(lane>>4)*4+reg, col=lane&15
        int r1 = r0 + 16;
        if (r0 < N_NODES) {
            out[(size_t)r0 * 128 + col0] = fmaxf(acc00[j] + bv0, 0.f);
            out[(size_t)r0 * 128 + col1] = fmaxf(acc01[j] + bv1, 0.f);
        }
        if (r1 < N_NODES) {
            out[(size_t)r1 * 128 + col0] = fmaxf(acc10[j] + bv0, 0.f);
            out[(size_t)r1 * 128 + col1] = fmaxf(acc11[j] + bv1, 0.f);
        }
    }
}

// ---------------------------------------------------------------------------
extern "C" void kernel_launch(void* const* d_in, const int* in_sizes, int n_in,
                              void* d_out, int out_size, void* d_ws, size_t ws_size,
                              hipStream_t stream) {
    const float* x    = (const float*)d_in[0];
    const int*   rows = (const int*)d_in[1];
    const int*   cols = (const int*)d_in[2];
    const float* vals = (const float*)d_in[3];
    const float* kern = (const float*)d_in[4];
    const float* bias = (const float*)d_in[5];
    float* out = (float*)d_out;
    char* ws = (char*)d_ws;

    // ws layout (~71.1 MB; ws proven >= 96.6 MB by R4/R5 big-path runs):
    //   [0, 38.4M)       zb bf16 [N,384] swizzled -- doubles as tmp int4
    //   [38.4M, +12.8M)  xb bf16 [N,128]
    //   [51.2M, +19.2M)  payload int2 (stride N_EDGES per support)
    //   [70.4M, +602K)   row_start (stride NP_PAD per support)
    //   + ghist/gcur/bucket_start (KBs) + WTb bf16 98,304 B
    const size_t OFF_ZB  = 0;
    const size_t OFF_XB  = 38400000;
    const size_t OFF_PAY = OFF_XB + 12800000;                       // 51,200,000
    const size_t OFF_RS  = OFF_PAY + (size_t)N_SUP * N_EDGES * 8;   // 70,400,000
    const size_t OFF_GH  = OFF_RS + (size_t)N_SUP * NP_PAD * 4;     // 71,002,112
    const size_t OFF_GC  = OFF_GH + 2368;
    const size_t OFF_BS  = OFF_GC + 2368;
    const size_t OFF_WT  = OFF_BS + 2368;                           // 71,009,216 (16-aligned)

    unsigned* zb           = (unsigned*)(ws + OFF_ZB);
    int4*     tmp          = (int4*)    (ws + OFF_ZB);   // overlaps zb
    unsigned* xbuf         = (unsigned*)(ws + OFF_XB);
    int2*     payload      = (int2*)    (ws + OFF_PAY);
    int*      row_start    = (int*)     (ws + OFF_RS);
    int*      ghist        = (int*)     (ws + OFF_GH);
    int*      gcur         = (int*)     (ws + OFF_GC);
    int*      bucket_start = (int*)     (ws + OFF_BS);
    uint4*    wtb          = (uint4*)   (ws + OFF_WT);

    const int row_blocks  = (N_NODES + 3) / 4;
    const int gemm_blocks = (N_NODES + 31) / 32;

    hipMemsetAsync(ghist, 0, N_SUP * NB * 4, stream);
    cvt_x_kernel<<<(N_NODES * 32 + 255) / 256, 256, 0, stream>>>(
        (const float4*)x, (uint2*)xbuf);
    cvt_w_kernel<<<(128 * 48 + 255) / 256, 256, 0, stream>>>(kern, wtb);
    bhist_kernel<<<dim3(NBLK_E, N_SUP), 256, 0, stream>>>(rows, ghist);
    bscan_kernel<<<dim3(1, N_SUP), 256, 0, stream>>>(ghist, bucket_start, gcur);
    part_kernel<<<dim3(NBLK_E, N_SUP), 256, 0, stream>>>(rows, cols, vals, gcur, tmp);
    rowsort_kernel<<<dim3(NB, N_SUP), 256, 0, stream>>>(tmp, bucket_start,
                                                        payload, row_start);
    gather_kernel<<<dim3(row_blocks, N_SUP), 256, 0, stream>>>(
        xbuf, payload, row_start, zb);
    mfma_gemm_kernel<<<gemm_blocks, 256, 0, stream>>>(
        (const char*)zb, (const char*)wtb, bias, out);
}

// Round 10
// 255.400 us; speedup vs baseline: 16.4960x; 1.1049x over previous
//
#include <hip/hip_runtime.h>

#define N_NODES 50000
#define N_EDGES 800000
#define N_SUP   3
#define FD      128
#define NP_PAD  50176        // per-support stride for row_start

#define NB      196          // buckets of 256 rows
#define RPB     256
#define EPB     3125         // 256 * 3125 = 800000
#define NBLK_E  256

typedef __attribute__((ext_vector_type(8))) short bf16x8;
typedef __attribute__((ext_vector_type(4))) float f32x4;

// bf16 helpers (RTN)
__device__ __forceinline__ unsigned rtn_bf16(float f) {
    unsigned u = __float_as_uint(f);
    return (u + 0x7FFFu + ((u >> 16) & 1u)) >> 16;
}
__device__ __forceinline__ float bf_lo(unsigned g) { return __uint_as_float(g << 16); }
__device__ __forceinline__ float bf_hi(unsigned g) { return __uint_as_float(g & 0xFFFF0000u); }

// ---------------------------------------------------------------------------
// K0a: x f32 [N,128] -> xb bf16 packed
__global__ __launch_bounds__(256) void cvt_x_kernel(const float4* __restrict__ x4,
                                                    uint2* __restrict__ xb) {
    int i = blockIdx.x * 256 + threadIdx.x;
    if (i >= N_NODES * 32) return;
    float4 v = x4[i];
    xb[i] = make_uint2(rtn_bf16(v.x) | (rtn_bf16(v.y) << 16),
                       rtn_bf16(v.z) | (rtn_bf16(v.w) << 16));
}

// ---------------------------------------------------------------------------
// K0b: W f32 [384,128] -> WT bf16 [col 128][k 384], quad-swizzled within each
// 4-quad (64 B) group: stored quad p holds logical quad (p&~3)|((p&3)^((col>>1)&3)).
__global__ __launch_bounds__(256) void cvt_w_kernel(const float* __restrict__ W,
                                                    uint4* __restrict__ wtb) {
    int tid = blockIdx.x * 256 + threadIdx.x;
    if (tid >= 128 * 48) return;
    int col = tid / 48, p = tid % 48;
    int qlog = (p & ~3) | ((p & 3) ^ ((col >> 1) & 3));
    int k0 = qlog * 8;
    unsigned w0 = rtn_bf16(W[(k0 + 0) * 128 + col]) | (rtn_bf16(W[(k0 + 1) * 128 + col]) << 16);
    unsigned w1 = rtn_bf16(W[(k0 + 2) * 128 + col]) | (rtn_bf16(W[(k0 + 3) * 128 + col]) << 16);
    unsigned w2 = rtn_bf16(W[(k0 + 4) * 128 + col]) | (rtn_bf16(W[(k0 + 5) * 128 + col]) << 16);
    unsigned w3 = rtn_bf16(W[(k0 + 6) * 128 + col]) | (rtn_bf16(W[(k0 + 7) * 128 + col]) << 16);
    wtb[col * 48 + p] = make_uint4(w0, w1, w2, w3);
}

// ---------------------------------------------------------------------------
// K1: per-block LDS bucket histogram -> ghist[sup][NB]
__global__ __launch_bounds__(256) void bhist_kernel(const int* __restrict__ rows,
                                                    int* __restrict__ ghist) {
    __shared__ int hist[NB];
    int t = threadIdx.x, y = blockIdx.y, blk = blockIdx.x;
    for (int i = t; i < NB; i += 256) hist[i] = 0;
    __syncthreads();
    size_t ebase = (size_t)y * N_EDGES + (size_t)blk * EPB;
    for (int i = t; i < EPB; i += 256)
        atomicAdd(&hist[rows[ebase + i] >> 8], 1);
    __syncthreads();
    for (int i = t; i < NB; i += 256)
        if (hist[i]) atomicAdd(&ghist[y * NB + i], hist[i]);
}

// ---------------------------------------------------------------------------
// K2: exclusive scan -> bucket_start[sup][NB+1], gcur[sup][NB]
__global__ __launch_bounds__(256) void bscan_kernel(const int* __restrict__ ghist,
                                                    int* __restrict__ bucket_start,
                                                    int* __restrict__ gcur) {
    __shared__ int s[256];
    int t = threadIdx.x, y = blockIdx.y;
    int cnt = (t < NB) ? ghist[y * NB + t] : 0;
    int val = cnt;
    s[t] = val; __syncthreads();
    for (int off = 1; off < 256; off <<= 1) {
        int v = (t >= off) ? s[t - off] : 0;
        __syncthreads();
        val += v; s[t] = val;
        __syncthreads();
    }
    int excl = val - cnt;
    if (t < NB) { bucket_start[y * (NB + 1) + t] = excl; gcur[y * NB + t] = excl; }
    if (t == NB - 1) bucket_start[y * (NB + 1) + NB] = val;
}

// ---------------------------------------------------------------------------
// K3: partition edges into bucket-grouped tmp.
// tmp entry int2: {col | (row&255)<<16, valbits}  (bucket implied by position)
__global__ __launch_bounds__(256) void part_kernel(const int* __restrict__ rows,
                                                   const int* __restrict__ cols,
                                                   const float* __restrict__ vals,
                                                   int* __restrict__ gcur,
                                                   int2* __restrict__ tmp) {
    __shared__ int2          eS[EPB];       // 25,000 B
    __shared__ unsigned      packed[EPB];   // 12,500 B
    __shared__ unsigned char bS[EPB];       //  3,125 B
    __shared__ int hist[NB], lstart[NB], lcur[NB], gbase[NB];
    __shared__ int s[256];

    int t = threadIdx.x, y = blockIdx.y, blk = blockIdx.x;
    size_t ebase = (size_t)y * N_EDGES + (size_t)blk * EPB;

    for (int i = t; i < NB; i += 256) hist[i] = 0;
    __syncthreads();
    for (int i = t; i < EPB; i += 256) {
        int r = rows[ebase + i];
        int c = cols[ebase + i];
        float v = vals[ebase + i];
        eS[i] = make_int2(c | ((r & 255) << 16), __float_as_int(v));
        bS[i] = (unsigned char)(r >> 8);
        atomicAdd(&hist[r >> 8], 1);
    }
    __syncthreads();

    int cnt = (t < NB) ? hist[t] : 0;
    int val = cnt;
    s[t] = val; __syncthreads();
    for (int off = 1; off < 256; off <<= 1) {
        int v = (t >= off) ? s[t - off] : 0;
        __syncthreads();
        val += v; s[t] = val;
        __syncthreads();
    }
    if (t < NB) {
        int excl = val - cnt;
        lstart[t] = excl; lcur[t] = excl;
        if (cnt > 0) gbase[t] = atomicAdd(&gcur[y * NB + t], cnt);
    }
    __syncthreads();

    for (int i = t; i < EPB; i += 256) {
        int b = bS[i];
        int pos = atomicAdd(&lcur[b], 1);
        packed[pos] = ((unsigned)b << 16) | (unsigned)i;
    }
    __syncthreads();

    for (int i = t; i < EPB; i += 256) {
        unsigned p = packed[i];
        int b = p >> 16, idx = p & 0xFFFF;
        tmp[(size_t)y * N_EDGES + gbase[b] + (i - lstart[b])] = eS[idx];
    }
}

// ---------------------------------------------------------------------------
// K4: two-pass per-bucket row sort (3 KB LDS -> high occupancy)
__global__ __launch_bounds__(256) void rowsort_kernel(const int2* __restrict__ tmp,
                                                      const int* __restrict__ bucket_start,
                                                      int2* __restrict__ payload,
                                                      int* __restrict__ row_start) {
    __shared__ int rhist[RPB], rcur[RPB];
    __shared__ int s[256];

    int t = threadIdx.x, b = blockIdx.x, y = blockIdx.y;
    int start = bucket_start[y * (NB + 1) + b];
    int end   = bucket_start[y * (NB + 1) + b + 1];
    int cnt   = end - start;

    rhist[t] = 0;
    __syncthreads();
    const int2* src = tmp + (size_t)y * N_EDGES + start;
    for (int i = t; i < cnt; i += 256)
        atomicAdd(&rhist[((unsigned)src[i].x) >> 16], 1);
    __syncthreads();

    int c0 = rhist[t];
    int val = c0;
    s[t] = val; __syncthreads();
    for (int off = 1; off < 256; off <<= 1) {
        int v = (t >= off) ? s[t - off] : 0;
        __syncthreads();
        val += v; s[t] = val;
        __syncthreads();
    }
    int excl = val - c0;
    rcur[t] = excl;
    int grow = b * RPB + t;
    if (grow < N_NODES) row_start[y * NP_PAD + grow] = start + excl;
    if (b == NB - 1 && t == 0) row_start[y * NP_PAD + N_NODES] = N_EDGES;
    __syncthreads();

    int2* dst = payload + (size_t)y * N_EDGES + start;
    for (int i = t; i < cnt; i += 256) {
        int2 e = src[i];
        int pos = atomicAdd(&rcur[((unsigned)e.x) >> 16], 1);
        dst[pos] = make_int2(e.x & 0xFFFF, e.y);
    }
}

// ---------------------------------------------------------------------------
// Gather: zb[r, y*128:+128] (bf16) = sum_e val_e * xb[col_e, :]
// 16 lanes per edge (uint4 = 16B/lane), 4 edges per wave-instruction-stream,
// 16/8/4 unroll cascade. Final cross-group reduce via shfl_xor(16,32).
// Store quad-swizzled by ((r>>1)&3) for the MFMA GEMM's global_load_lds path.
__global__ __launch_bounds__(256) void gather_kernel(const uint4* __restrict__ xb4,
                                                     const int2* __restrict__ payload,
                                                     const int* __restrict__ row_start,
                                                     uint4* __restrict__ zb4) {
    int wid  = threadIdx.x >> 6;
    int lane = threadIdx.x & 63;
    int grp  = lane >> 4;      // edge slot 0..3
    int l16  = lane & 15;      // feats [l16*8, l16*8+8)
    int r = blockIdx.x * 4 + wid;
    if (r >= N_NODES) return;

    const int*  rs  = row_start + blockIdx.y * NP_PAD;
    const int2* pay = payload + (size_t)blockIdx.y * N_EDGES;
    int s = rs[r];
    int e = rs[r + 1];

    float a0 = 0.f, a1 = 0.f, a2 = 0.f, a3 = 0.f;
    float a4 = 0.f, a5 = 0.f, a6 = 0.f, a7 = 0.f;

    int i = s;
    for (; i + 16 <= e; i += 16) {
        int2 pA = pay[i + grp];
        int2 pB = pay[i + 4 + grp];
        int2 pC = pay[i + 8 + grp];
        int2 pD = pay[i + 12 + grp];
        uint4 gA = xb4[(size_t)pA.x * 16 + l16];
        uint4 gB = xb4[(size_t)pB.x * 16 + l16];
        uint4 gC = xb4[(size_t)pC.x * 16 + l16];
        uint4 gD = xb4[(size_t)pD.x * 16 + l16];
        float vA = __int_as_float(pA.y), vB = __int_as_float(pB.y);
        float vC = __int_as_float(pC.y), vD = __int_as_float(pD.y);
        a0 = fmaf(vA, bf_lo(gA.x), a0); a1 = fmaf(vA, bf_hi(gA.x), a1);
        a2 = fmaf(vA, bf_lo(gA.y), a2); a3 = fmaf(vA, bf_hi(gA.y), a3);
        a4 = fmaf(vA, bf_lo(gA.z), a4); a5 = fmaf(vA, bf_hi(gA.z), a5);
        a6 = fmaf(vA, bf_lo(gA.w), a6); a7 = fmaf(vA, bf_hi(gA.w), a7);
        a0 = fmaf(vB, bf_lo(gB.x), a0); a1 = fmaf(vB, bf_hi(gB.x), a1);
        a2 = fmaf(vB, bf_lo(gB.y), a2); a3 = fmaf(vB, bf_hi(gB.y), a3);
        a4 = fmaf(vB, bf_lo(gB.z), a4); a5 = fmaf(vB, bf_hi(gB.z), a5);
        a6 = fmaf(vB, bf_lo(gB.w), a6); a7 = fmaf(vB, bf_hi(gB.w), a7);
        a0 = fmaf(vC, bf_lo(gC.x), a0); a1 = fmaf(vC, bf_hi(gC.x), a1);
        a2 = fmaf(vC, bf_lo(gC.y), a2); a3 = fmaf(vC, bf_hi(gC.y), a3);
        a4 = fmaf(vC, bf_lo(gC.z), a4); a5 = fmaf(vC, bf_hi(gC.z), a5);
        a6 = fmaf(vC, bf_lo(gC.w), a6); a7 = fmaf(vC, bf_hi(gC.w), a7);
        a0 = fmaf(vD, bf_lo(gD.x), a0); a1 = fmaf(vD, bf_hi(gD.x), a1);
        a2 = fmaf(vD, bf_lo(gD.y), a2); a3 = fmaf(vD, bf_hi(gD.y), a3);
        a4 = fmaf(vD, bf_lo(gD.z), a4); a5 = fmaf(vD, bf_hi(gD.z), a5);
        a6 = fmaf(vD, bf_lo(gD.w), a6); a7 = fmaf(vD, bf_hi(gD.w), a7);
    }
    for (; i + 8 <= e; i += 8) {
        int2 pA = pay[i + grp];
        int2 pB = pay[i + 4 + grp];
        uint4 gA = xb4[(size_t)pA.x * 16 + l16];
        uint4 gB = xb4[(size_t)pB.x * 16 + l16];
        float vA = __int_as_float(pA.y), vB = __int_as_float(pB.y);
        a0 = fmaf(vA, bf_lo(gA.x), a0); a1 = fmaf(vA, bf_hi(gA.x), a1);
        a2 = fmaf(vA, bf_lo(gA.y), a2); a3 = fmaf(vA, bf_hi(gA.y), a3);
        a4 = fmaf(vA, bf_lo(gA.z), a4); a5 = fmaf(vA, bf_hi(gA.z), a5);
        a6 = fmaf(vA, bf_lo(gA.w), a6); a7 = fmaf(vA, bf_hi(gA.w), a7);
        a0 = fmaf(vB, bf_lo(gB.x), a0); a1 = fmaf(vB, bf_hi(gB.x), a1);
        a2 = fmaf(vB, bf_lo(gB.y), a2); a3 = fmaf(vB, bf_hi(gB.y), a3);
        a4 = fmaf(vB, bf_lo(gB.z), a4); a5 = fmaf(vB, bf_hi(gB.z), a5);
        a6 = fmaf(vB, bf_lo(gB.w), a6); a7 = fmaf(vB, bf_hi(gB.w), a7);
    }
    for (; i < e; i += 4) {
        int idx = i + grp;
        if (idx < e) {
            int2 p = pay[idx];
            uint4 g = xb4[(size_t)p.x * 16 + l16];
            float v = __int_as_float(p.y);
            a0 = fmaf(v, bf_lo(g.x), a0); a1 = fmaf(v, bf_hi(g.x), a1);
            a2 = fmaf(v, bf_lo(g.y), a2); a3 = fmaf(v, bf_hi(g.y), a3);
            a4 = fmaf(v, bf_lo(g.z), a4); a5 = fmaf(v, bf_hi(g.z), a5);
            a6 = fmaf(v, bf_lo(g.w), a6); a7 = fmaf(v, bf_hi(g.w), a7);
        }
    }

    // reduce across the 4 edge-groups (lanes l16, l16+16, l16+32, l16+48)
    a0 += __shfl_xor(a0, 16); a0 += __shfl_xor(a0, 32);
    a1 += __shfl_xor(a1, 16); a1 += __shfl_xor(a1, 32);
    a2 += __shfl_xor(a2, 16); a2 += __shfl_xor(a2, 32);
    a3 += __shfl_xor(a3, 16); a3 += __shfl_xor(a3, 32);
    a4 += __shfl_xor(a4, 16); a4 += __shfl_xor(a4, 32);
    a5 += __shfl_xor(a5, 16); a5 += __shfl_xor(a5, 32);
    a6 += __shfl_xor(a6, 16); a6 += __shfl_xor(a6, 32);
    a7 += __shfl_xor(a7, 16); a7 += __shfl_xor(a7, 32);

    if (grp == 0) {
        unsigned q = ((unsigned)(r >> 1)) & 3u;   // quad swizzle
        uint4 o = make_uint4(rtn_bf16(a0) | (rtn_bf16(a1) << 16),
                             rtn_bf16(a2) | (rtn_bf16(a3) << 16),
                             rtn_bf16(a4) | (rtn_bf16(a5) << 16),
                             rtn_bf16(a6) | (rtn_bf16(a7) << 16));
        zb4[(size_t)r * 48 + blockIdx.y * 16 + (l16 ^ q)] = o;
    }
}

// ---------------------------------------------------------------------------
// MFMA GEMM: out[32-row tile, 128] = relu(z[tile,384]bf16 @ W[384,128]bf16 + bias)
__global__ __launch_bounds__(256) void mfma_gemm_kernel(const char* __restrict__ zb_sw,
                                                        const char* __restrict__ wtb_sw,
                                                        const float* __restrict__ bias,
                                                        float* __restrict__ out) {
    __shared__ __align__(16) char zS[2048];    // 32 rows x 32 k bf16
    __shared__ __align__(16) char wS[8192];    // 128 cols x 32 k bf16

    const int t    = threadIdx.x;
    const int lane = t & 63;
    const int wv   = t >> 6;
    const int row0 = blockIdx.x * 32;
    const int m = lane >> 4;
    const int n = lane & 15;

    const int ar0   = n;
    const int ar1   = 16 + n;
    const int aoff0 = ar0 * 64 + ((m ^ ((ar0 >> 1) & 3)) * 16);
    const int aoff1 = ar1 * 64 + ((m ^ ((ar1 >> 1) & 3)) * 16);
    const int col0  = wv * 32 + n;
    const int col1  = col0 + 16;
    const int boff0 = col0 * 64 + ((m ^ ((col0 >> 1) & 3)) * 16);
    const int boff1 = col1 * 64 + ((m ^ ((col1 >> 1) & 3)) * 16);

    f32x4 acc00 = {0.f, 0.f, 0.f, 0.f};
    f32x4 acc01 = acc00, acc10 = acc00, acc11 = acc00;

    for (int ks = 0; ks < 12; ++ks) {
        __syncthreads();
        if (t < 128) {
            const char* asrc = zb_sw + (size_t)(row0 + (t >> 2)) * 768 + ks * 64 + (t & 3) * 16;
            __builtin_amdgcn_global_load_lds(
                (const __attribute__((address_space(1))) void*)asrc,
                (__attribute__((address_space(3))) void*)(zS + t * 16), 16, 0, 0);
        }
        {
            const char* bsrc0 = wtb_sw + (t >> 2) * 768 + ks * 64 + (t & 3) * 16;
            __builtin_amdgcn_global_load_lds(
                (const __attribute__((address_space(1))) void*)bsrc0,
                (__attribute__((address_space(3))) void*)(wS + t * 16), 16, 0, 0);
            int i = t + 256;
            const char* bsrc1 = wtb_sw + (i >> 2) * 768 + ks * 64 + (i & 3) * 16;
            __builtin_amdgcn_global_load_lds(
                (const __attribute__((address_space(1))) void*)bsrc1,
                (__attribute__((address_space(3))) void*)(wS + i * 16), 16, 0, 0);
        }
        __syncthreads();

        bf16x8 a0 = *(const bf16x8*)(zS + aoff0);
        bf16x8 a1 = *(const bf16x8*)(zS + aoff1);
        bf16x8 b0 = *(const bf16x8*)(wS + boff0);
        bf16x8 b1 = *(const bf16x8*)(wS + boff1);
        acc00 = __builtin_amdgcn_mfma_f32_16x16x32_bf16(a0, b0, acc00, 0, 0, 0);
        acc01 = __builtin_amdgcn_mfma_f32_16x16x32_bf16(a0, b1, acc01, 0, 0, 0);
        acc10 = __builtin_amdgcn_mfma_f32_16x16x32_bf16(a1, b0, acc10, 0, 0, 0);
        acc11 = __builtin_amdgcn_mfma_f32_16x16x32_bf16(a1, b1, acc11, 0, 0, 0);
    }

    float bv0 = bias[col0], bv1 = bias[col1];
    #pragma unroll
    for (int j = 0; j < 4; ++j) {
        int r0 = row0 + m * 4 + j;
        int r1 = r0 + 16;
        if (r0 < N_NODES) {
            out[(size_t)r0 * 128 + col0] = fmaxf(acc00[j] + bv0, 0.f);
            out[(size_t)r0 * 128 + col1] = fmaxf(acc01[j] + bv1, 0.f);
        }
        if (r1 < N_NODES) {
            out[(size_t)r1 * 128 + col0] = fmaxf(acc10[j] + bv0, 0.f);
            out[(size_t)r1 * 128 + col1] = fmaxf(acc11[j] + bv1, 0.f);
        }
    }
}

// ---------------------------------------------------------------------------
extern "C" void kernel_launch(void* const* d_in, const int* in_sizes, int n_in,
                              void* d_out, int out_size, void* d_ws, size_t ws_size,
                              hipStream_t stream) {
    const float* x    = (const float*)d_in[0];
    const int*   rows = (const int*)d_in[1];
    const int*   cols = (const int*)d_in[2];
    const float* vals = (const float*)d_in[3];
    const float* kern = (const float*)d_in[4];
    const float* bias = (const float*)d_in[5];
    float* out = (float*)d_out;
    char* ws = (char*)d_ws;

    // ws layout (~71.1 MB):
    //   [0, 38.4M)       zb bf16 [N,384] swizzled -- first 19.2M doubles as tmp int2
    //   [38.4M, +12.8M)  xb bf16 [N,128]
    //   [51.2M, +19.2M)  payload int2 (stride N_EDGES per support)
    //   [70.4M, +602K)   row_start (stride NP_PAD per support)
    //   + ghist/gcur/bucket_start (KBs) + WTb bf16 98,304 B
    const size_t OFF_ZB  = 0;
    const size_t OFF_XB  = 38400000;
    const size_t OFF_PAY = OFF_XB + 12800000;                       // 51,200,000
    const size_t OFF_RS  = OFF_PAY + (size_t)N_SUP * N_EDGES * 8;   // 70,400,000
    const size_t OFF_GH  = OFF_RS + (size_t)N_SUP * NP_PAD * 4;     // 71,002,112
    const size_t OFF_GC  = OFF_GH + 2368;
    const size_t OFF_BS  = OFF_GC + 2368;
    const size_t OFF_WT  = OFF_BS + 2368;                           // 71,009,216 (16-aligned)

    unsigned* zb           = (unsigned*)(ws + OFF_ZB);
    int2*     tmp          = (int2*)    (ws + OFF_ZB);   // overlaps zb
    unsigned* xbuf         = (unsigned*)(ws + OFF_XB);
    int2*     payload      = (int2*)    (ws + OFF_PAY);
    int*      row_start    = (int*)     (ws + OFF_RS);
    int*      ghist        = (int*)     (ws + OFF_GH);
    int*      gcur         = (int*)     (ws + OFF_GC);
    int*      bucket_start = (int*)     (ws + OFF_BS);
    uint4*    wtb          = (uint4*)   (ws + OFF_WT);

    const int row_blocks  = (N_NODES + 3) / 4;
    const int gemm_blocks = (N_NODES + 31) / 32;

    hipMemsetAsync(ghist, 0, N_SUP * NB * 4, stream);
    cvt_x_kernel<<<(N_NODES * 32 + 255) / 256, 256, 0, stream>>>(
        (const float4*)x, (uint2*)xbuf);
    cvt_w_kernel<<<(128 * 48 + 255) / 256, 256, 0, stream>>>(kern, wtb);
    bhist_kernel<<<dim3(NBLK_E, N_SUP), 256, 0, stream>>>(rows, ghist);
    bscan_kernel<<<dim3(1, N_SUP), 256, 0, stream>>>(ghist, bucket_start, gcur);
    part_kernel<<<dim3(NBLK_E, N_SUP), 256, 0, stream>>>(rows, cols, vals, gcur, tmp);
    rowsort_kernel<<<dim3(NB, N_SUP), 256, 0, stream>>>(tmp, bucket_start,
                                                        payload, row_start);
    gather_kernel<<<dim3(row_blocks, N_SUP), 256, 0, stream>>>(
        (const uint4*)xbuf, payload, row_start, (uint4*)zb);
    mfma_gemm_kernel<<<gemm_blocks, 256, 0, stream>>>(
        (const char*)zb, (const char*)wtb, bias, out);
}